// Round 1
// baseline (1400.152 us; speedup 1.0000x reference)
//
#include <hip/hip_runtime.h>
#include <math.h>

#define TT 2048
#define DD 512
#define NH 8
#define HDD 64
#define EPS_F 1e-8f

// ---------------------------------------------------------------------------
// W2 prep: combined real-valued output-projection weight
//   [ o_wr  o_wi ]
//   [-o_wi  o_wr ]   (rows = [y_re | y_im], cols = [out_re | out_im])
// ---------------------------------------------------------------------------
__global__ void w2prep_kernel(const float* __restrict__ o_wr, const float* __restrict__ o_wi,
                              const float* __restrict__ o_br, const float* __restrict__ o_bi,
                              float* __restrict__ W2, float* __restrict__ b2)
{
    int idx = blockIdx.x * 256 + threadIdx.x;   // 0 .. 1024*1024-1
    int i = idx >> 10, j = idx & 1023;
    float val;
    if (i < 512) val = (j < 512) ?  o_wr[i * 512 + j]         : o_wi[i * 512 + (j - 512)];
    else         val = (j < 512) ? -o_wi[(i - 512) * 512 + j] : o_wr[(i - 512) * 512 + (j - 512)];
    W2[idx] = val;
    if (idx < 1024) b2[idx] = (idx < 512) ? o_br[idx] : o_bi[idx - 512];
}

// ---------------------------------------------------------------------------
// GEMM1: Y1[2048 x 3072] = X[2048 x 512] @ [Wq_r|Wq_i|Wk_r|Wk_i|Wv_r|Wv_i] + bias
// ---------------------------------------------------------------------------
__global__ __launch_bounds__(256) void gemm_qkv_kernel(
    const float* __restrict__ X,
    const float* __restrict__ Wq_r, const float* __restrict__ Wq_i,
    const float* __restrict__ Wk_r, const float* __restrict__ Wk_i,
    const float* __restrict__ Wv_r, const float* __restrict__ Wv_i,
    const float* __restrict__ bq_r, const float* __restrict__ bq_i,
    const float* __restrict__ bk_r, const float* __restrict__ bk_i,
    const float* __restrict__ bv_r, const float* __restrict__ bv_i,
    float* __restrict__ Y)
{
    __shared__ float As[16][68];   // transposed A tile: As[k][m]
    __shared__ float Bs[16][68];
    const int tid = threadIdx.x;
    const int bx = blockIdx.x, by = blockIdx.y;
    const int grp = (bx * 64) >> 9;         // which of the 6 weight groups
    const int ncol0 = (bx * 64) & 511;      // column offset within group
    const float* W; const float* Bb;
    switch (grp) {
      case 0: W = Wq_r; Bb = bq_r; break;
      case 1: W = Wq_i; Bb = bq_i; break;
      case 2: W = Wk_r; Bb = bk_r; break;
      case 3: W = Wk_i; Bb = bk_i; break;
      case 4: W = Wv_r; Bb = bv_r; break;
      default: W = Wv_i; Bb = bv_i; break;
    }
    const int tx = tid & 15, ty = tid >> 4;
    const int am = tid >> 2, ak4 = (tid & 3) << 2;   // A staging: row, k-offset
    const int bk = tid >> 4, bn4 = (tid & 15) << 2;  // B staging: k row, col-offset
    float acc[4][4] = {{0.f}};

    for (int k0 = 0; k0 < 512; k0 += 16) {
        float4 av = *(const float4*)&X[(by * 64 + am) * 512 + k0 + ak4];
        float4 bv = *(const float4*)&W[(k0 + bk) * 512 + ncol0 + bn4];
        __syncthreads();   // protect previous iteration's readers
        As[ak4 + 0][am] = av.x;
        As[ak4 + 1][am] = av.y;
        As[ak4 + 2][am] = av.z;
        As[ak4 + 3][am] = av.w;
        *(float4*)&Bs[bk][bn4] = bv;
        __syncthreads();
        #pragma unroll
        for (int kk = 0; kk < 16; ++kk) {
            float4 a = *(const float4*)&As[kk][ty * 4];
            float4 b = *(const float4*)&Bs[kk][tx * 4];
            acc[0][0] += a.x*b.x; acc[0][1] += a.x*b.y; acc[0][2] += a.x*b.z; acc[0][3] += a.x*b.w;
            acc[1][0] += a.y*b.x; acc[1][1] += a.y*b.y; acc[1][2] += a.y*b.z; acc[1][3] += a.y*b.w;
            acc[2][0] += a.z*b.x; acc[2][1] += a.z*b.y; acc[2][2] += a.z*b.z; acc[2][3] += a.z*b.w;
            acc[3][0] += a.w*b.x; acc[3][1] += a.w*b.y; acc[3][2] += a.w*b.z; acc[3][3] += a.w*b.w;
        }
    }
    float4 bias = *(const float4*)&Bb[ncol0 + tx * 4];
    int row = by * 64 + ty * 4, col = bx * 64 + tx * 4;
    #pragma unroll
    for (int i = 0; i < 4; ++i) {
        float4 o;
        o.x = acc[i][0] + bias.x; o.y = acc[i][1] + bias.y;
        o.z = acc[i][2] + bias.z; o.w = acc[i][3] + bias.w;
        *(float4*)&Y[(row + i) * 3072 + col] = o;
    }
}

// ---------------------------------------------------------------------------
// Features (in place on Y1): q -> q_phase*q_gate, k -> conj(k_phase)*k_gate
// ---------------------------------------------------------------------------
__global__ void feature_kernel(float* __restrict__ Y1,
                               float* __restrict__ gq_arr, float* __restrict__ gk_arr)
{
    int idx = blockIdx.x * 256 + threadIdx.x;   // 0 .. 2048*512-1
    int t = idx >> 9, d = idx & 511;
    float* row = Y1 + t * 3072;
    float qr = row[d], qi = row[512 + d];
    float g = sqrtf(qr * qr + qi * qi);
    float f = g / (g + EPS_F);
    row[d] = qr * f; row[512 + d] = qi * f;
    gq_arr[idx] = g;
    float kr = row[1024 + d], ki = row[1536 + d];
    g = sqrtf(kr * kr + ki * ki);
    f = g / (g + EPS_F);
    row[1024 + d] = kr * f; row[1536 + d] = -ki * f;   // conj
    gk_arr[idx] = g;
}

// ---------------------------------------------------------------------------
// Sequential decayed scan + readout.
// grid = 32 blocks: (head h = bid>>2, v-chunk vc = bid&3), 256 threads.
// Thread (v_local = tid>>4, kq = tid&15) owns S[v][k] for k = kq*4..kq*4+3.
// Per-step features staged in LDS (double-buffered global prefetch).
// LDS lqk[k] = float4 {qf_re, qf_im, kk_re, kk_im}, XOR-swizzled.
// ---------------------------------------------------------------------------
__global__ __launch_bounds__(256) void scan_kernel(
    const float* __restrict__ F,     // Y1 features [2048][3072]
    const float* __restrict__ GQ,    // [2048][512]
    const float* __restrict__ GK,    // [2048][512]
    const float* __restrict__ lgs, const float* __restrict__ lgz,
    const float* __restrict__ phs,
    float* __restrict__ Y2)          // [2048][1024]  (re | im halves)
{
    __shared__ float4 lqk[64];
    __shared__ float2 lv[64];
    __shared__ float  lgq[64];
    __shared__ float  lgk[64];

    const int tid = threadIdx.x;
    const int h  = blockIdx.x >> 2;
    const int vc = blockIdx.x & 3;
    const int lane = tid & 63;
    const int v_local = tid >> 4;
    const int kq = tid & 15;
    const int vglob = vc * 16 + v_local;

    // decay params
    float xs = lgs[h];
    float sps = fmaxf(xs, 0.f) + log1pf(expf(-fabsf(xs)));
    float radius = expf(-sps);
    float ph = phs[h];
    float ar = radius * cosf(ph);
    float ai = radius * sinf(ph);
    float xz = lgz[h];
    float az = expf(-(fmaxf(xz, 0.f) + log1pf(expf(-fabsf(xz)))));

    // ---- staging source pointers (idx0 = tid, idx1 = tid+256) ----
    const float* src0; int st0;
    const float* src1; int st1;
    {
        int idx = tid, seg = idx >> 6, jj = idx & 63;
        if (seg < 6)      { src0 = F  + seg * 512 + h * 64 + jj; st0 = 3072; }
        else if (seg == 6){ src0 = GQ + h * 64 + jj;             st0 = 512; }
        else              { src0 = GK + h * 64 + jj;             st0 = 512; }
        idx = tid + 256; seg = idx >> 6; jj = idx & 63;
        if (seg < 6)      { src1 = F  + seg * 512 + h * 64 + jj; st1 = 3072; }
        else if (seg == 6){ src1 = GQ + h * 64 + jj;             st1 = 512; }
        else              { src1 = GK + h * 64 + jj;             st1 = 512; }
    }
    // ---- staging destination pointers ----
    float* dst0; float* dst1;
    {
        int idx = tid, seg = idx >> 6, jj = idx & 63;
        if (seg < 4)       dst0 = (float*)((char*)lqk + (((jj << 4) ^ ((jj >> 3) << 4)) + seg * 4));
        else if (seg == 4) dst0 = &lv[jj].x;
        else if (seg == 5) dst0 = &lv[jj].y;
        else if (seg == 6) dst0 = &lgq[jj];
        else               dst0 = &lgk[jj];
        idx = tid + 256; seg = idx >> 6; jj = idx & 63;
        if (seg < 4)       dst1 = (float*)((char*)lqk + (((jj << 4) ^ ((jj >> 3) << 4)) + seg * 4));
        else if (seg == 4) dst1 = &lv[jj].x;
        else if (seg == 5) dst1 = &lv[jj].y;
        else if (seg == 6) dst1 = &lgq[jj];
        else               dst1 = &lgk[jj];
    }
    // ---- swizzled LDS read pointers for this thread's 4 k values ----
    const float4* rdp[4];
    #pragma unroll
    for (int j = 0; j < 4; ++j) {
        int k = kq * 4 + j;
        rdp[j] = (const float4*)((const char*)lqk + ((k << 4) ^ ((k >> 3) << 4)));
    }

    float Sr[4] = {0.f, 0.f, 0.f, 0.f};
    float Si[4] = {0.f, 0.f, 0.f, 0.f};
    float Zl = 0.f;

    float r0 = *src0; src0 += st0;
    float r1 = *src1; src1 += st1;

    for (int t = 0; t < TT; ++t) {
        *dst0 = r0;
        *dst1 = r1;
        __syncthreads();
        if (t < TT - 1) {           // prefetch next step under compute
            r0 = *src0; src0 += st0;
            r1 = *src1; src1 += st1;
        }
        float2 vv = lv[vglob];
        float gql = lgq[lane];
        float gkl = lgk[lane];
        float nr = 0.f, ni = 0.f;
        #pragma unroll
        for (int j = 0; j < 4; ++j) {
            float4 f = *rdp[j];     // {qfr, qfi, kkr, kki}
            float sr = Sr[j], si = Si[j];
            float tr = ar * sr - ai * si + vv.x * f.z - vv.y * f.w;
            float ti = ar * si + ai * sr + vv.x * f.w + vv.y * f.z;
            Sr[j] = tr; Si[j] = ti;
            nr += tr * f.x - ti * f.y;
            ni += tr * f.y + ti * f.x;
        }
        // numerator: reduce over the 16 lanes of this v-group
        nr += __shfl_xor(nr, 1);  ni += __shfl_xor(ni, 1);
        nr += __shfl_xor(nr, 2);  ni += __shfl_xor(ni, 2);
        nr += __shfl_xor(nr, 4);  ni += __shfl_xor(ni, 4);
        nr += __shfl_xor(nr, 8);  ni += __shfl_xor(ni, 8);
        // denominator: wave-replicated Z state (lane l owns Z[l])
        Zl = az * Zl + gkl;
        float p = Zl * gql;
        p += __shfl_xor(p, 1);  p += __shfl_xor(p, 2);  p += __shfl_xor(p, 4);
        p += __shfl_xor(p, 8);  p += __shfl_xor(p, 16); p += __shfl_xor(p, 32);
        if (kq == 0) {
            float inv = 1.f / (p + EPS_F);
            Y2[t * 1024 + h * 64 + vglob]       = nr * inv;
            Y2[t * 1024 + 512 + h * 64 + vglob] = ni * inv;
        }
        __syncthreads();
    }
}

// ---------------------------------------------------------------------------
// GEMM2: out = Y2[2048 x 1024] @ W2[1024 x 1024] + b2, epilogue interleaves
// complex (mode 1) or writes real part only (mode 0).
// ---------------------------------------------------------------------------
__global__ __launch_bounds__(256) void gemm_out_kernel(
    const float* __restrict__ A,    // Y2
    const float* __restrict__ W,    // W2
    const float* __restrict__ bias, // b2
    float* __restrict__ out, int out_mode)
{
    if (out_mode == 0 && blockIdx.x >= 8) return;   // imag columns unused
    __shared__ float As[16][68];
    __shared__ float Bs[16][68];
    const int tid = threadIdx.x;
    const int bx = blockIdx.x, by = blockIdx.y;
    const int tx = tid & 15, ty = tid >> 4;
    const int am = tid >> 2, ak4 = (tid & 3) << 2;
    const int bk = tid >> 4, bn4 = (tid & 15) << 2;
    float acc[4][4] = {{0.f}};

    for (int k0 = 0; k0 < 1024; k0 += 16) {
        float4 av = *(const float4*)&A[(by * 64 + am) * 1024 + k0 + ak4];
        float4 bv = *(const float4*)&W[(k0 + bk) * 1024 + bx * 64 + bn4];
        __syncthreads();
        As[ak4 + 0][am] = av.x;
        As[ak4 + 1][am] = av.y;
        As[ak4 + 2][am] = av.z;
        As[ak4 + 3][am] = av.w;
        *(float4*)&Bs[bk][bn4] = bv;
        __syncthreads();
        #pragma unroll
        for (int kk = 0; kk < 16; ++kk) {
            float4 a = *(const float4*)&As[kk][ty * 4];
            float4 b = *(const float4*)&Bs[kk][tx * 4];
            acc[0][0] += a.x*b.x; acc[0][1] += a.x*b.y; acc[0][2] += a.x*b.z; acc[0][3] += a.x*b.w;
            acc[1][0] += a.y*b.x; acc[1][1] += a.y*b.y; acc[1][2] += a.y*b.z; acc[1][3] += a.y*b.w;
            acc[2][0] += a.z*b.x; acc[2][1] += a.z*b.y; acc[2][2] += a.z*b.z; acc[2][3] += a.z*b.w;
            acc[3][0] += a.w*b.x; acc[3][1] += a.w*b.y; acc[3][2] += a.w*b.z; acc[3][3] += a.w*b.w;
        }
    }
    int row = by * 64 + ty * 4, col = bx * 64 + tx * 4;
    #pragma unroll
    for (int i = 0; i < 4; ++i) {
        int r = row + i;
        #pragma unroll
        for (int j2 = 0; j2 < 4; ++j2) {
            int j = col + j2;
            float val = acc[i][j2] + bias[j];
            if (out_mode == 1) {
                int off = (j < 512) ? (r * 1024 + 2 * j) : (r * 1024 + 2 * (j - 512) + 1);
                out[off] = val;
            } else {
                if (j < 512) out[r * 512 + j] = val;
            }
        }
    }
}

// ---------------------------------------------------------------------------
extern "C" void kernel_launch(void* const* d_in, const int* in_sizes, int n_in,
                              void* d_out, int out_size, void* d_ws, size_t ws_size,
                              hipStream_t stream)
{
    const float* x    = (const float*)d_in[0];
    const float* q_wr = (const float*)d_in[1];
    const float* q_wi = (const float*)d_in[2];
    const float* q_br = (const float*)d_in[3];
    const float* q_bi = (const float*)d_in[4];
    const float* k_wr = (const float*)d_in[5];
    const float* k_wi = (const float*)d_in[6];
    const float* k_br = (const float*)d_in[7];
    const float* k_bi = (const float*)d_in[8];
    const float* v_wr = (const float*)d_in[9];
    const float* v_wi = (const float*)d_in[10];
    const float* v_br = (const float*)d_in[11];
    const float* v_bi = (const float*)d_in[12];
    const float* o_wr = (const float*)d_in[13];
    const float* o_wi = (const float*)d_in[14];
    const float* o_br = (const float*)d_in[15];
    const float* o_bi = (const float*)d_in[16];
    const float* log_decay_s = (const float*)d_in[17];
    const float* log_decay_z = (const float*)d_in[18];
    const float* phase       = (const float*)d_in[19];

    float* ws = (float*)d_ws;
    float* Y1 = ws;                              // 2048*3072
    float* gq = Y1 + 2048 * 3072;                // 2048*512
    float* gk = gq + 2048 * 512;                 // 2048*512
    float* Y2 = gk + 2048 * 512;                 // 2048*1024
    float* W2 = Y2 + 2048 * 1024;                // 1024*1024
    float* b2 = W2 + 1024 * 1024;                // 1024

    int out_mode = (out_size == 2048 * 512 * 2) ? 1 : 0;

    w2prep_kernel<<<4096, 256, 0, stream>>>(o_wr, o_wi, o_br, o_bi, W2, b2);

    dim3 g1(48, 32);
    gemm_qkv_kernel<<<g1, 256, 0, stream>>>(x, q_wr, q_wi, k_wr, k_wi, v_wr, v_wi,
                                            q_br, q_bi, k_br, k_bi, v_br, v_bi, Y1);

    feature_kernel<<<4096, 256, 0, stream>>>(Y1, gq, gk);

    scan_kernel<<<32, 256, 0, stream>>>(Y1, gq, gk, log_decay_s, log_decay_z, phase, Y2);

    dim3 g2(16, 32);
    gemm_out_kernel<<<g2, 256, 0, stream>>>(Y2, W2, b2, (float*)d_out, out_mode);
}

// Round 2
// 391.974 us; speedup vs baseline: 3.5720x; 3.5720x over previous
//
#include <hip/hip_runtime.h>
#include <math.h>

#define TT 2048
#define NH 8
#define HDD 64
#define CL 32          // chunk length
#define NC 64          // number of chunks
#define EPS_F 1e-8f

__device__ __forceinline__ float2 cmul(float2 a, float2 b) {
    return make_float2(a.x*b.x - a.y*b.y, a.x*b.y + a.y*b.x);
}

// ---------------------------------------------------------------------------
// W2 prep: combined real-valued output-projection weight
// ---------------------------------------------------------------------------
__global__ void w2prep_kernel(const float* __restrict__ o_wr, const float* __restrict__ o_wi,
                              const float* __restrict__ o_br, const float* __restrict__ o_bi,
                              float* __restrict__ W2, float* __restrict__ b2)
{
    int idx = blockIdx.x * 256 + threadIdx.x;
    int i = idx >> 10, j = idx & 1023;
    float val;
    if (i < 512) val = (j < 512) ?  o_wr[i * 512 + j]         : o_wi[i * 512 + (j - 512)];
    else         val = (j < 512) ? -o_wi[(i - 512) * 512 + j] : o_wr[(i - 512) * 512 + (j - 512)];
    W2[idx] = val;
    if (idx < 1024) b2[idx] = (idx < 512) ? o_br[idx] : o_bi[idx - 512];
}

// ---------------------------------------------------------------------------
// GEMM1: Y1[2048 x 3072] = X @ [Wq_r|Wq_i|Wk_r|Wk_i|Wv_r|Wv_i] + bias
// ---------------------------------------------------------------------------
__global__ __launch_bounds__(256) void gemm_qkv_kernel(
    const float* __restrict__ X,
    const float* __restrict__ Wq_r, const float* __restrict__ Wq_i,
    const float* __restrict__ Wk_r, const float* __restrict__ Wk_i,
    const float* __restrict__ Wv_r, const float* __restrict__ Wv_i,
    const float* __restrict__ bq_r, const float* __restrict__ bq_i,
    const float* __restrict__ bk_r, const float* __restrict__ bk_i,
    const float* __restrict__ bv_r, const float* __restrict__ bv_i,
    float* __restrict__ Y)
{
    __shared__ float As[16][68];
    __shared__ float Bs[16][68];
    const int tid = threadIdx.x;
    const int bx = blockIdx.x, by = blockIdx.y;
    const int grp = (bx * 64) >> 9;
    const int ncol0 = (bx * 64) & 511;
    const float* W; const float* Bb;
    switch (grp) {
      case 0: W = Wq_r; Bb = bq_r; break;
      case 1: W = Wq_i; Bb = bq_i; break;
      case 2: W = Wk_r; Bb = bk_r; break;
      case 3: W = Wk_i; Bb = bk_i; break;
      case 4: W = Wv_r; Bb = bv_r; break;
      default: W = Wv_i; Bb = bv_i; break;
    }
    const int tx = tid & 15, ty = tid >> 4;
    const int am = tid >> 2, ak4 = (tid & 3) << 2;
    const int bk = tid >> 4, bn4 = (tid & 15) << 2;
    float acc[4][4] = {{0.f}};

    for (int k0 = 0; k0 < 512; k0 += 16) {
        float4 av = *(const float4*)&X[(by * 64 + am) * 512 + k0 + ak4];
        float4 bv = *(const float4*)&W[(k0 + bk) * 512 + ncol0 + bn4];
        __syncthreads();
        As[ak4 + 0][am] = av.x;
        As[ak4 + 1][am] = av.y;
        As[ak4 + 2][am] = av.z;
        As[ak4 + 3][am] = av.w;
        *(float4*)&Bs[bk][bn4] = bv;
        __syncthreads();
        #pragma unroll
        for (int kk = 0; kk < 16; ++kk) {
            float4 a = *(const float4*)&As[kk][ty * 4];
            float4 b = *(const float4*)&Bs[kk][tx * 4];
            acc[0][0] += a.x*b.x; acc[0][1] += a.x*b.y; acc[0][2] += a.x*b.z; acc[0][3] += a.x*b.w;
            acc[1][0] += a.y*b.x; acc[1][1] += a.y*b.y; acc[1][2] += a.y*b.z; acc[1][3] += a.y*b.w;
            acc[2][0] += a.z*b.x; acc[2][1] += a.z*b.y; acc[2][2] += a.z*b.z; acc[2][3] += a.z*b.w;
            acc[3][0] += a.w*b.x; acc[3][1] += a.w*b.y; acc[3][2] += a.w*b.z; acc[3][3] += a.w*b.w;
        }
    }
    float4 bias = *(const float4*)&Bb[ncol0 + tx * 4];
    int row = by * 64 + ty * 4, col = bx * 64 + tx * 4;
    #pragma unroll
    for (int i = 0; i < 4; ++i) {
        float4 o;
        o.x = acc[i][0] + bias.x; o.y = acc[i][1] + bias.y;
        o.z = acc[i][2] + bias.z; o.w = acc[i][3] + bias.w;
        *(float4*)&Y[(row + i) * 3072 + col] = o;
    }
}

// ---------------------------------------------------------------------------
// Features (in place on Y1): q -> q_phase*q_gate, k -> conj(k_phase)*k_gate
// ---------------------------------------------------------------------------
__global__ void feature_kernel(float* __restrict__ Y1,
                               float* __restrict__ gq_arr, float* __restrict__ gk_arr)
{
    int idx = blockIdx.x * 256 + threadIdx.x;
    int t = idx >> 9, d = idx & 511;
    float* row = Y1 + t * 3072;
    float qr = row[d], qi = row[512 + d];
    float g = sqrtf(qr * qr + qi * qi);
    float f = g / (g + EPS_F);
    row[d] = qr * f; row[512 + d] = qi * f;
    gq_arr[idx] = g;
    float kr = row[1024 + d], ki = row[1536 + d];
    g = sqrtf(kr * kr + ki * ki);
    f = g / (g + EPS_F);
    row[1024 + d] = kr * f; row[1536 + d] = -ki * f;   // conj
    gk_arr[idx] = g;
}

// ---------------------------------------------------------------------------
// chunkstate: Sc[c][h][vd][k] = sum_u alpha^(31-u) v[u][vd]*kk[u][k]  (complex)
//             Zc[c][h][k]     = sum_u az^(31-u)    gk[u][k]
// grid 512 = 64 chunks x 8 heads, 256 threads
// ---------------------------------------------------------------------------
__global__ __launch_bounds__(256) void chunkstate_kernel(
    const float* __restrict__ F, const float* __restrict__ GK,
    const float* __restrict__ lgs, const float* __restrict__ lgz,
    const float* __restrict__ phs,
    float2* __restrict__ Sc, float* __restrict__ Zc)
{
    __shared__ float2 swv[CL][65];
    __shared__ float2 skk[CL][65];
    __shared__ float  sgk[CL][65];
    __shared__ float2 s_apow[CL + 1];
    __shared__ float  s_azpow[CL + 1];

    const int tid = threadIdx.x;
    const int c = blockIdx.x & 63;
    const int h = blockIdx.x >> 6;

    if (tid <= CL) {
        float xs = lgs[h];
        float sps = fmaxf(xs, 0.f) + log1pf(expf(-fabsf(xs)));
        float ph = phs[h];
        float r = expf(-sps * (float)tid);
        s_apow[tid] = make_float2(r * cosf(ph * (float)tid), r * sinf(ph * (float)tid));
        float xz = lgz[h];
        float spz = fmaxf(xz, 0.f) + log1pf(expf(-fabsf(xz)));
        s_azpow[tid] = expf(-spz * (float)tid);
    }
    __syncthreads();

    const int u = tid >> 3, k0 = (tid & 7) << 3;
    {
        const float* row = F + (size_t)(c * CL + u) * 3072 + h * HDD + k0;
        float vre[8], vim[8], kre[8], kim[8], gg[8];
        *(float4*)(vre)     = *(const float4*)(row + 2048);
        *(float4*)(vre + 4) = *(const float4*)(row + 2052);
        *(float4*)(vim)     = *(const float4*)(row + 2560);
        *(float4*)(vim + 4) = *(const float4*)(row + 2564);
        *(float4*)(kre)     = *(const float4*)(row + 1024);
        *(float4*)(kre + 4) = *(const float4*)(row + 1028);
        *(float4*)(kim)     = *(const float4*)(row + 1536);
        *(float4*)(kim + 4) = *(const float4*)(row + 1540);
        const float* grow = GK + (size_t)(c * CL + u) * 512 + h * HDD + k0;
        *(float4*)(gg)      = *(const float4*)(grow);
        *(float4*)(gg + 4)  = *(const float4*)(grow + 4);
        float2 w = s_apow[CL - 1 - u];
        float  wz = s_azpow[CL - 1 - u];
        #pragma unroll
        for (int i = 0; i < 8; ++i) {
            float2 vv = make_float2(vre[i], vim[i]);
            swv[u][k0 + i] = cmul(w, vv);
            skk[u][k0 + i] = make_float2(kre[i], kim[i]);
            sgk[u][k0 + i] = wz * gg[i];
        }
    }
    __syncthreads();

    const int vd = tid >> 2, ks = tid & 3;
    float2 acc[16];
    #pragma unroll
    for (int j = 0; j < 16; ++j) acc[j] = make_float2(0.f, 0.f);
    for (int uu = 0; uu < CL; ++uu) {
        float2 wv = swv[uu][vd];
        #pragma unroll
        for (int j = 0; j < 16; ++j) {
            float2 kv = skk[uu][ks + (j << 2)];
            acc[j].x += wv.x * kv.x - wv.y * kv.y;
            acc[j].y += wv.x * kv.y + wv.y * kv.x;
        }
    }
    float2* out = Sc + ((size_t)(c * NH + h) << 12);
    #pragma unroll
    for (int j = 0; j < 16; ++j) out[vd * 64 + ks + (j << 2)] = acc[j];

    if (tid < 64) {
        float z = 0.f;
        #pragma unroll
        for (int uu = 0; uu < CL; ++uu) z += sgk[uu][tid];
        Zc[(c * NH + h) * 64 + tid] = z;
    }
}

// ---------------------------------------------------------------------------
// chunkscan: in-place exclusive prefix over chunks (elementwise, parallel).
// After: Sc[c] holds prefix state S_end(c-1); Zc[c] holds Z prefix.
// grid (8 heads, 17 slices), 256 threads
// ---------------------------------------------------------------------------
__global__ __launch_bounds__(256) void chunkscan_kernel(
    const float* __restrict__ lgs, const float* __restrict__ lgz,
    const float* __restrict__ phs,
    float2* __restrict__ Sc, float* __restrict__ Zc)
{
    const int h = blockIdx.x;
    const int slice = blockIdx.y;
    if (slice < 16) {
        float xs = lgs[h];
        float sps = fmaxf(xs, 0.f) + log1pf(expf(-fabsf(xs)));
        float ph = phs[h];
        float r = expf(-sps * (float)CL);
        float2 aL = make_float2(r * cosf(ph * (float)CL), r * sinf(ph * (float)CL));
        int idx = slice * 256 + threadIdx.x;
        float2 prev = make_float2(0.f, 0.f);
        for (int c = 0; c < NC; ++c) {
            float2* p = Sc + ((size_t)(c * NH + h) << 12) + idx;
            float2 tmp = *p;
            *p = prev;
            prev = make_float2(aL.x * prev.x - aL.y * prev.y + tmp.x,
                               aL.x * prev.y + aL.y * prev.x + tmp.y);
        }
    } else if (threadIdx.x < 64) {
        float xz = lgz[h];
        float spz = fmaxf(xz, 0.f) + log1pf(expf(-fabsf(xz)));
        float azL = expf(-spz * (float)CL);
        float prev = 0.f;
        for (int c = 0; c < NC; ++c) {
            float* p = Zc + (c * NH + h) * 64 + threadIdx.x;
            float tmp = *p;
            *p = prev;
            prev = azL * prev + tmp;
        }
    }
}

// ---------------------------------------------------------------------------
// chunkout: per (chunk,head): intra (masked decayed score matrix) + inter
// (prefix state), normalized readout -> Y2.
// grid 512 = 64 chunks x 8 heads, 256 threads
// ---------------------------------------------------------------------------
__global__ __launch_bounds__(256) void chunkout_kernel(
    const float* __restrict__ F, const float* __restrict__ GQ, const float* __restrict__ GK,
    const float2* __restrict__ Sp, const float* __restrict__ Zp,
    const float* __restrict__ lgs, const float* __restrict__ lgz,
    const float* __restrict__ phs,
    float* __restrict__ Y2)
{
    __shared__ float2 sqf[CL][65];
    __shared__ float2 skkT[64][33];
    __shared__ float2 sv[CL][65];
    __shared__ float  sgq[CL][65];
    __shared__ float  sgkT[64][33];
    __shared__ float2 sW[CL][33];
    __shared__ float  sDinv[CL];
    __shared__ float  sZp[64];
    __shared__ float2 s_apow[CL + 1];
    __shared__ float  s_azpow[CL + 1];

    const int tid = threadIdx.x;
    const int c = blockIdx.x & 63;
    const int h = blockIdx.x >> 6;

    if (tid <= CL) {
        float xs = lgs[h];
        float sps = fmaxf(xs, 0.f) + log1pf(expf(-fabsf(xs)));
        float ph = phs[h];
        float r = expf(-sps * (float)tid);
        s_apow[tid] = make_float2(r * cosf(ph * (float)tid), r * sinf(ph * (float)tid));
        float xz = lgz[h];
        float spz = fmaxf(xz, 0.f) + log1pf(expf(-fabsf(xz)));
        s_azpow[tid] = expf(-spz * (float)tid);
    }
    if (tid < 64) sZp[tid] = Zp[(c * NH + h) * 64 + tid];

    const int u = tid >> 3, k0 = (tid & 7) << 3;
    {
        const float* row = F + (size_t)(c * CL + u) * 3072 + h * HDD + k0;
        float qre[8], qim[8], kre[8], kim[8], vre[8], vim[8], gqv[8], gkv[8];
        *(float4*)(qre)     = *(const float4*)(row);
        *(float4*)(qre + 4) = *(const float4*)(row + 4);
        *(float4*)(qim)     = *(const float4*)(row + 512);
        *(float4*)(qim + 4) = *(const float4*)(row + 516);
        *(float4*)(kre)     = *(const float4*)(row + 1024);
        *(float4*)(kre + 4) = *(const float4*)(row + 1028);
        *(float4*)(kim)     = *(const float4*)(row + 1536);
        *(float4*)(kim + 4) = *(const float4*)(row + 1540);
        *(float4*)(vre)     = *(const float4*)(row + 2048);
        *(float4*)(vre + 4) = *(const float4*)(row + 2052);
        *(float4*)(vim)     = *(const float4*)(row + 2560);
        *(float4*)(vim + 4) = *(const float4*)(row + 2564);
        const float* gqrow = GQ + (size_t)(c * CL + u) * 512 + h * HDD + k0;
        const float* gkrow = GK + (size_t)(c * CL + u) * 512 + h * HDD + k0;
        *(float4*)(gqv)     = *(const float4*)(gqrow);
        *(float4*)(gqv + 4) = *(const float4*)(gqrow + 4);
        *(float4*)(gkv)     = *(const float4*)(gkrow);
        *(float4*)(gkv + 4) = *(const float4*)(gkrow + 4);
        #pragma unroll
        for (int i = 0; i < 8; ++i) {
            sqf[u][k0 + i]  = make_float2(qre[i], qim[i]);
            skkT[k0 + i][u] = make_float2(kre[i], kim[i]);
            sv[u][k0 + i]   = make_float2(vre[i], vim[i]);
            sgq[u][k0 + i]  = gqv[i];
            sgkT[k0 + i][u] = gkv[i];
        }
    }
    __syncthreads();

    // ---- step 1: score matrices, decay-mask, denominator ----
    {
        const int t = tid >> 3, u4 = tid & 7;
        float2 A[4];
        float Ad[4] = {0.f, 0.f, 0.f, 0.f};
        #pragma unroll
        for (int j = 0; j < 4; ++j) A[j] = make_float2(0.f, 0.f);
        float zdot = 0.f;
        for (int k = 0; k < 64; ++k) {
            float2 q = sqf[t][k];
            float g = sgq[t][k];
            zdot += sZp[k] * g;
            #pragma unroll
            for (int j = 0; j < 4; ++j) {
                float2 kv = skkT[k][u4 + (j << 3)];
                A[j].x += q.x * kv.x - q.y * kv.y;
                A[j].y += q.x * kv.y + q.y * kv.x;
                Ad[j] += g * sgkT[k][u4 + (j << 3)];
            }
        }
        float denp = 0.f;
        #pragma unroll
        for (int j = 0; j < 4; ++j) {
            int uu = u4 + (j << 3);
            float2 wv = make_float2(0.f, 0.f);
            if (uu <= t) {
                float2 p = s_apow[t - uu];
                wv = cmul(p, A[j]);
                denp += s_azpow[t - uu] * Ad[j];
            }
            sW[t][uu] = wv;
        }
        denp += __shfl_xor(denp, 1);
        denp += __shfl_xor(denp, 2);
        denp += __shfl_xor(denp, 4);
        if (u4 == 0) {
            float den = denp + s_azpow[t + 1] * zdot;
            sDinv[t] = 1.f / (den + EPS_F);
        }
    }
    __syncthreads();

    // ---- step 2/3: num = W@V (intra) + apow[t+1] * Sp@qf (inter); write y ----
    {
        const int t = tid >> 3, vs = tid & 7;
        float2 acc[8];
        #pragma unroll
        for (int j = 0; j < 8; ++j) acc[j] = make_float2(0.f, 0.f);
        for (int uu = 0; uu < CL; ++uu) {
            float2 w = sW[t][uu];
            #pragma unroll
            for (int j = 0; j < 8; ++j) {
                float2 vv = sv[uu][vs + (j << 3)];
                acc[j].x += w.x * vv.x - w.y * vv.y;
                acc[j].y += w.x * vv.y + w.y * vv.x;
            }
        }
        const float2 fac = s_apow[t + 1];
        const float2* spb = Sp + ((size_t)(c * NH + h) << 12);
        #pragma unroll
        for (int j = 0; j < 8; ++j) {
            const float2* sprow = spb + (size_t)(vs + (j << 3)) * 64;
            float2 b = make_float2(0.f, 0.f);
            #pragma unroll 8
            for (int k = 0; k < 64; ++k) {
                float2 q = sqf[t][k];
                float2 s = sprow[k];
                b.x += s.x * q.x - s.y * q.y;
                b.y += s.x * q.y + s.y * q.x;
            }
            acc[j].x += fac.x * b.x - fac.y * b.y;
            acc[j].y += fac.x * b.y + fac.y * b.x;
        }
        float dinv = sDinv[t];
        float* orow = Y2 + (size_t)(c * CL + t) * 1024 + h * HDD;
        #pragma unroll
        for (int j = 0; j < 8; ++j) {
            int vdd = vs + (j << 3);
            orow[vdd]       = acc[j].x * dinv;
            orow[512 + vdd] = acc[j].y * dinv;
        }
    }
}

// ---------------------------------------------------------------------------
// GEMM2: out = Y2[2048 x 1024] @ W2[1024 x 1024] + b2
// ---------------------------------------------------------------------------
__global__ __launch_bounds__(256) void gemm_out_kernel(
    const float* __restrict__ A,
    const float* __restrict__ W,
    const float* __restrict__ bias,
    float* __restrict__ out, int out_mode)
{
    if (out_mode == 0 && blockIdx.x >= 8) return;
    __shared__ float As[16][68];
    __shared__ float Bs[16][68];
    const int tid = threadIdx.x;
    const int bx = blockIdx.x, by = blockIdx.y;
    const int tx = tid & 15, ty = tid >> 4;
    const int am = tid >> 2, ak4 = (tid & 3) << 2;
    const int bk = tid >> 4, bn4 = (tid & 15) << 2;
    float acc[4][4] = {{0.f}};

    for (int k0 = 0; k0 < 1024; k0 += 16) {
        float4 av = *(const float4*)&A[(by * 64 + am) * 1024 + k0 + ak4];
        float4 bv = *(const float4*)&W[(k0 + bk) * 1024 + bx * 64 + bn4];
        __syncthreads();
        As[ak4 + 0][am] = av.x;
        As[ak4 + 1][am] = av.y;
        As[ak4 + 2][am] = av.z;
        As[ak4 + 3][am] = av.w;
        *(float4*)&Bs[bk][bn4] = bv;
        __syncthreads();
        #pragma unroll
        for (int kk = 0; kk < 16; ++kk) {
            float4 a = *(const float4*)&As[kk][ty * 4];
            float4 b = *(const float4*)&Bs[kk][tx * 4];
            acc[0][0] += a.x*b.x; acc[0][1] += a.x*b.y; acc[0][2] += a.x*b.z; acc[0][3] += a.x*b.w;
            acc[1][0] += a.y*b.x; acc[1][1] += a.y*b.y; acc[1][2] += a.y*b.z; acc[1][3] += a.y*b.w;
            acc[2][0] += a.z*b.x; acc[2][1] += a.z*b.y; acc[2][2] += a.z*b.z; acc[2][3] += a.z*b.w;
            acc[3][0] += a.w*b.x; acc[3][1] += a.w*b.y; acc[3][2] += a.w*b.z; acc[3][3] += a.w*b.w;
        }
    }
    int row = by * 64 + ty * 4, col = bx * 64 + tx * 4;
    #pragma unroll
    for (int i = 0; i < 4; ++i) {
        int r = row + i;
        #pragma unroll
        for (int j2 = 0; j2 < 4; ++j2) {
            int j = col + j2;
            float val = acc[i][j2] + bias[j];
            if (out_mode == 1) {
                int off = (j < 512) ? (r * 1024 + 2 * j) : (r * 1024 + 2 * (j - 512) + 1);
                out[off] = val;
            } else {
                if (j < 512) out[r * 512 + j] = val;
            }
        }
    }
}

// ---------------------------------------------------------------------------
extern "C" void kernel_launch(void* const* d_in, const int* in_sizes, int n_in,
                              void* d_out, int out_size, void* d_ws, size_t ws_size,
                              hipStream_t stream)
{
    const float* x    = (const float*)d_in[0];
    const float* q_wr = (const float*)d_in[1];
    const float* q_wi = (const float*)d_in[2];
    const float* q_br = (const float*)d_in[3];
    const float* q_bi = (const float*)d_in[4];
    const float* k_wr = (const float*)d_in[5];
    const float* k_wi = (const float*)d_in[6];
    const float* k_br = (const float*)d_in[7];
    const float* k_bi = (const float*)d_in[8];
    const float* v_wr = (const float*)d_in[9];
    const float* v_wi = (const float*)d_in[10];
    const float* v_br = (const float*)d_in[11];
    const float* v_bi = (const float*)d_in[12];
    const float* o_wr = (const float*)d_in[13];
    const float* o_wi = (const float*)d_in[14];
    const float* o_br = (const float*)d_in[15];
    const float* o_bi = (const float*)d_in[16];
    const float* log_decay_s = (const float*)d_in[17];
    const float* log_decay_z = (const float*)d_in[18];
    const float* phase       = (const float*)d_in[19];

    float* ws = (float*)d_ws;
    float* Y1  = ws;                       // 2048*3072 = 6291456
    float* gq  = Y1 + 6291456;             // 1048576
    float* gk  = gq + 1048576;             // 1048576
    float* Y2  = gk + 1048576;             // 2097152
    float* W2  = Y2 + 2097152;             // 1048576
    float* b2  = W2 + 1048576;             // 1024
    float* Scf = b2 + 1024;                // 64*8*4096*2 = 4194304
    float* Zcf = Scf + 4194304;            // 32768

    int out_mode = (out_size == 2048 * 512 * 2) ? 1 : 0;

    w2prep_kernel<<<4096, 256, 0, stream>>>(o_wr, o_wi, o_br, o_bi, W2, b2);

    dim3 g1(48, 32);
    gemm_qkv_kernel<<<g1, 256, 0, stream>>>(x, q_wr, q_wi, k_wr, k_wi, v_wr, v_wi,
                                            q_br, q_bi, k_br, k_bi, v_br, v_bi, Y1);

    feature_kernel<<<4096, 256, 0, stream>>>(Y1, gq, gk);

    chunkstate_kernel<<<512, 256, 0, stream>>>(Y1, gk, log_decay_s, log_decay_z, phase,
                                               (float2*)Scf, Zcf);

    chunkscan_kernel<<<dim3(8, 17), 256, 0, stream>>>(log_decay_s, log_decay_z, phase,
                                                      (float2*)Scf, Zcf);

    chunkout_kernel<<<512, 256, 0, stream>>>(Y1, gq, gk, (const float2*)Scf, Zcf,
                                             log_decay_s, log_decay_z, phase, Y2);

    dim3 g2(16, 32);
    gemm_out_kernel<<<g2, 256, 0, stream>>>(Y2, W2, b2, (float*)d_out, out_mode);
}

// Round 3
// 167.521 us; speedup vs baseline: 8.3581x; 2.3398x over previous
//
#include <hip/hip_runtime.h>
#include <math.h>

#define TT 2048
#define NH 8
#define HDD 64
#define CL 32          // chunk length
#define NC 64          // number of chunks
#define EPS_F 1e-8f

typedef __attribute__((ext_vector_type(8))) _Float16 half8;
typedef __attribute__((ext_vector_type(4))) _Float16 half4;
typedef __attribute__((ext_vector_type(4))) float    f32x4;

__device__ __forceinline__ float2 cmul(float2 a, float2 b) {
    return make_float2(a.x*b.x - a.y*b.y, a.x*b.y + a.y*b.x);
}

// ---------------------------------------------------------------------------
// xconv: fp32 -> fp16, 4 elems/thread
// ---------------------------------------------------------------------------
__global__ void xconv_kernel(const float* __restrict__ X, _Float16* __restrict__ Xh)
{
    int i4 = blockIdx.x * 256 + threadIdx.x;
    float4 v = ((const float4*)X)[i4];
    half4 o;
    o[0] = (_Float16)v.x; o[1] = (_Float16)v.y;
    o[2] = (_Float16)v.z; o[3] = (_Float16)v.w;
    ((half4*)Xh)[i4] = o;
}

// ---------------------------------------------------------------------------
// biasprep: pack GEMM1 bias [3072] and GEMM2 bias [1024] (fp32)
// ---------------------------------------------------------------------------
__global__ void biasprep_kernel(
    const float* __restrict__ bq_r, const float* __restrict__ bq_i,
    const float* __restrict__ bk_r, const float* __restrict__ bk_i,
    const float* __restrict__ bv_r, const float* __restrict__ bv_i,
    const float* __restrict__ o_br, const float* __restrict__ o_bi,
    float* __restrict__ ball, float* __restrict__ b2a)
{
    int idx = blockIdx.x * 256 + threadIdx.x;   // 0..4095
    if (idx < 3072) {
        int grp = idx >> 9, d = idx & 511;
        float v;
        switch (grp) {
          case 0: v = bq_r[d]; break;
          case 1: v = bq_i[d]; break;
          case 2: v = bk_r[d]; break;
          case 3: v = bk_i[d]; break;
          case 4: v = bv_r[d]; break;
          default: v = bv_i[d]; break;
        }
        ball[idx] = v;
    } else {
        int j = idx - 3072;   // 0..1023
        b2a[j] = (j < 512) ? o_br[j] : o_bi[j - 512];
    }
}

// ---------------------------------------------------------------------------
// wconv: transpose-convert the 6 projection weights [512][512] fp32
//        into WT_all [3072][512] fp16  (WT[n][k] = W[k][n])
// grid (8 k-tiles, 8 n-tiles, 6 groups)
// ---------------------------------------------------------------------------
__global__ __launch_bounds__(256) void wconv_kernel(
    const float* __restrict__ Wq_r, const float* __restrict__ Wq_i,
    const float* __restrict__ Wk_r, const float* __restrict__ Wk_i,
    const float* __restrict__ Wv_r, const float* __restrict__ Wv_i,
    _Float16* __restrict__ WT)
{
    __shared__ float tile[64][65];
    const int tid = threadIdx.x;
    const int k0 = blockIdx.x * 64, n0 = blockIdx.y * 64, g = blockIdx.z;
    const float* W;
    switch (g) {
      case 0: W = Wq_r; break;
      case 1: W = Wq_i; break;
      case 2: W = Wk_r; break;
      case 3: W = Wk_i; break;
      case 4: W = Wv_r; break;
      default: W = Wv_i; break;
    }
    #pragma unroll
    for (int it = 0; it < 16; ++it) {
        int idx = it * 256 + tid;
        tile[idx >> 6][idx & 63] = W[(size_t)(k0 + (idx >> 6)) * 512 + n0 + (idx & 63)];
    }
    __syncthreads();
    #pragma unroll
    for (int it = 0; it < 16; ++it) {
        int idx = it * 256 + tid;
        int nr = idx >> 6, kc = idx & 63;
        WT[(size_t)(g * 512 + n0 + nr) * 512 + k0 + kc] = (_Float16)tile[kc][nr];
    }
}

// ---------------------------------------------------------------------------
// w2prep: combined real output-projection weight, transposed + fp16:
//   W2[i][j]: [ o_wr  o_wi ; -o_wi  o_wr ];  W2T[j][i] = W2[i][j]
// grid (16 i-tiles, 16 j-tiles)
// ---------------------------------------------------------------------------
__global__ __launch_bounds__(256) void w2prep_kernel(
    const float* __restrict__ o_wr, const float* __restrict__ o_wi,
    _Float16* __restrict__ W2T)
{
    __shared__ float tile[64][65];
    const int tid = threadIdx.x;
    const int i0 = blockIdx.x * 64, j0 = blockIdx.y * 64;
    const float* src; float sgn; int io, jo;
    if (i0 < 512) {
        if (j0 < 512) { src = o_wr; sgn = 1.f;  io = i0; jo = j0; }
        else          { src = o_wi; sgn = 1.f;  io = i0; jo = j0 - 512; }
    } else {
        if (j0 < 512) { src = o_wi; sgn = -1.f; io = i0 - 512; jo = j0; }
        else          { src = o_wr; sgn = 1.f;  io = i0 - 512; jo = j0 - 512; }
    }
    #pragma unroll
    for (int it = 0; it < 16; ++it) {
        int idx = it * 256 + tid;
        tile[idx >> 6][idx & 63] = sgn * src[(size_t)(io + (idx >> 6)) * 512 + jo + (idx & 63)];
    }
    __syncthreads();
    #pragma unroll
    for (int it = 0; it < 16; ++it) {
        int idx = it * 256 + tid;
        int nr = idx >> 6, kc = idx & 63;
        W2T[(size_t)(j0 + nr) * 1024 + i0 + kc] = (_Float16)tile[kc][nr];
    }
}

// ---------------------------------------------------------------------------
// MFMA fp16 GEMM: C[M][ldc] = A[M][K] @ BT[N][K]^T + bias
// 128x128 tile, BK=32, 256 threads (4 waves 2x2), reg-staged LDS with
// XOR-swizzled k-chunks (q' = q ^ ((row>>1)&3)) for conflict-light ds_reads.
// wmode 0: C[row*ldc+col]; wmode 1: complex interleave (GEMM2 full output).
// ---------------------------------------------------------------------------
__global__ __launch_bounds__(256) void gemm_f16_kernel(
    const _Float16* __restrict__ A,
    const _Float16* __restrict__ BT,
    const float* __restrict__ bias,
    float* __restrict__ C,
    int K, int ldc, int wmode)
{
    __shared__ _Float16 sA[128 * 32];
    __shared__ _Float16 sB[128 * 32];
    const int tid = threadIdx.x;
    const int m0 = blockIdx.y * 128, n0 = blockIdx.x * 128;
    const int lane = tid & 63;
    const int w = tid >> 6, wm = w >> 1, wn = w & 1;

    f32x4 acc[4][4];
    #pragma unroll
    for (int i = 0; i < 4; ++i)
        #pragma unroll
        for (int j = 0; j < 4; ++j) { f32x4 z = {0.f, 0.f, 0.f, 0.f}; acc[i][j] = z; }

    const int r0 = tid >> 2, r1 = (tid >> 2) + 64;
    const int sq = tid & 3;
    const _Float16* gA0 = A + (size_t)(m0 + r0) * K + (sq ^ ((r0 >> 1) & 3)) * 8;
    const _Float16* gA1 = A + (size_t)(m0 + r1) * K + (sq ^ ((r1 >> 1) & 3)) * 8;
    const _Float16* gB0 = BT + (size_t)(n0 + r0) * K + (sq ^ ((r0 >> 1) & 3)) * 8;
    const _Float16* gB1 = BT + (size_t)(n0 + r1) * K + (sq ^ ((r1 >> 1) & 3)) * 8;
    _Float16* wA0 = &sA[r0 * 32 + sq * 8];
    _Float16* wA1 = &sA[r1 * 32 + sq * 8];
    _Float16* wB0 = &sB[r0 * 32 + sq * 8];
    _Float16* wB1 = &sB[r1 * 32 + sq * 8];

    float4 pa0 = *(const float4*)gA0, pa1 = *(const float4*)gA1;
    float4 pb0 = *(const float4*)gB0, pb1 = *(const float4*)gB1;

    const int arow = wm * 64 + (lane & 15);
    const int brow = wn * 64 + (lane & 15);
    const int nsteps = K >> 5;

    for (int ks = 0; ks < nsteps; ++ks) {
        *(float4*)wA0 = pa0; *(float4*)wA1 = pa1;
        *(float4*)wB0 = pb0; *(float4*)wB1 = pb1;
        __syncthreads();
        if (ks + 1 < nsteps) {
            int ko = (ks + 1) << 5;
            pa0 = *(const float4*)(gA0 + ko); pa1 = *(const float4*)(gA1 + ko);
            pb0 = *(const float4*)(gB0 + ko); pb1 = *(const float4*)(gB1 + ko);
        }
        half8 af[4], bf[4];
        #pragma unroll
        for (int mt = 0; mt < 4; ++mt) {
            int r = arow + mt * 16;
            int qp = (lane >> 4) ^ ((r >> 1) & 3);
            af[mt] = *(half8*)&sA[r * 32 + qp * 8];
        }
        #pragma unroll
        for (int nt = 0; nt < 4; ++nt) {
            int r = brow + nt * 16;
            int qp = (lane >> 4) ^ ((r >> 1) & 3);
            bf[nt] = *(half8*)&sB[r * 32 + qp * 8];
        }
        #pragma unroll
        for (int mt = 0; mt < 4; ++mt)
            #pragma unroll
            for (int nt = 0; nt < 4; ++nt)
                acc[mt][nt] = __builtin_amdgcn_mfma_f32_16x16x32_f16(af[mt], bf[nt], acc[mt][nt], 0, 0, 0);
        __syncthreads();
    }

    const int crow0 = m0 + wm * 64 + (lane >> 4) * 4;
    const int ccol0 = n0 + wn * 64 + (lane & 15);
    #pragma unroll
    for (int mt = 0; mt < 4; ++mt) {
        #pragma unroll
        for (int nt = 0; nt < 4; ++nt) {
            int col = ccol0 + nt * 16;
            float b = bias[col];
            #pragma unroll
            for (int rg = 0; rg < 4; ++rg) {
                int row = crow0 + mt * 16 + rg;
                float val = acc[mt][nt][rg] + b;
                if (wmode == 0) {
                    C[(size_t)row * ldc + col] = val;
                } else {
                    int off = (col < 512) ? (row * 1024 + 2 * col) : (row * 1024 + 2 * (col - 512) + 1);
                    C[off] = val;
                }
            }
        }
    }
}

// ---------------------------------------------------------------------------
// Features (in place on Y1): q -> q_phase*q_gate, k -> conj(k_phase)*k_gate
// ---------------------------------------------------------------------------
__global__ void feature_kernel(float* __restrict__ Y1,
                               float* __restrict__ gq_arr, float* __restrict__ gk_arr)
{
    int idx = blockIdx.x * 256 + threadIdx.x;
    int t = idx >> 9, d = idx & 511;
    float* row = Y1 + t * 3072;
    float qr = row[d], qi = row[512 + d];
    float g = sqrtf(qr * qr + qi * qi);
    float f = g / (g + EPS_F);
    row[d] = qr * f; row[512 + d] = qi * f;
    gq_arr[idx] = g;
    float kr = row[1024 + d], ki = row[1536 + d];
    g = sqrtf(kr * kr + ki * ki);
    f = g / (g + EPS_F);
    row[1024 + d] = kr * f; row[1536 + d] = -ki * f;   // conj
    gk_arr[idx] = g;
}

// ---------------------------------------------------------------------------
// chunkstate: Sc[c][h][vd][k] = sum_u alpha^(31-u) v[u][vd]*kk[u][k]  (complex)
//             Zc[c][h][k]     = sum_u az^(31-u)    gk[u][k]
// ---------------------------------------------------------------------------
__global__ __launch_bounds__(256) void chunkstate_kernel(
    const float* __restrict__ F, const float* __restrict__ GK,
    const float* __restrict__ lgs, const float* __restrict__ lgz,
    const float* __restrict__ phs,
    float2* __restrict__ Sc, float* __restrict__ Zc)
{
    __shared__ float2 swv[CL][65];
    __shared__ float2 skk[CL][65];
    __shared__ float  sgk[CL][65];
    __shared__ float2 s_apow[CL + 1];
    __shared__ float  s_azpow[CL + 1];

    const int tid = threadIdx.x;
    const int c = blockIdx.x & 63;
    const int h = blockIdx.x >> 6;

    if (tid <= CL) {
        float xs = lgs[h];
        float sps = fmaxf(xs, 0.f) + log1pf(expf(-fabsf(xs)));
        float ph = phs[h];
        float r = expf(-sps * (float)tid);
        s_apow[tid] = make_float2(r * cosf(ph * (float)tid), r * sinf(ph * (float)tid));
        float xz = lgz[h];
        float spz = fmaxf(xz, 0.f) + log1pf(expf(-fabsf(xz)));
        s_azpow[tid] = expf(-spz * (float)tid);
    }
    __syncthreads();

    const int u = tid >> 3, k0 = (tid & 7) << 3;
    {
        const float* row = F + (size_t)(c * CL + u) * 3072 + h * HDD + k0;
        float vre[8], vim[8], kre[8], kim[8], gg[8];
        *(float4*)(vre)     = *(const float4*)(row + 2048);
        *(float4*)(vre + 4) = *(const float4*)(row + 2052);
        *(float4*)(vim)     = *(const float4*)(row + 2560);
        *(float4*)(vim + 4) = *(const float4*)(row + 2564);
        *(float4*)(kre)     = *(const float4*)(row + 1024);
        *(float4*)(kre + 4) = *(const float4*)(row + 1028);
        *(float4*)(kim)     = *(const float4*)(row + 1536);
        *(float4*)(kim + 4) = *(const float4*)(row + 1540);
        const float* grow = GK + (size_t)(c * CL + u) * 512 + h * HDD + k0;
        *(float4*)(gg)      = *(const float4*)(grow);
        *(float4*)(gg + 4)  = *(const float4*)(grow + 4);
        float2 w = s_apow[CL - 1 - u];
        float  wz = s_azpow[CL - 1 - u];
        #pragma unroll
        for (int i = 0; i < 8; ++i) {
            float2 vv = make_float2(vre[i], vim[i]);
            swv[u][k0 + i] = cmul(w, vv);
            skk[u][k0 + i] = make_float2(kre[i], kim[i]);
            sgk[u][k0 + i] = wz * gg[i];
        }
    }
    __syncthreads();

    const int vd = tid >> 2, ks = tid & 3;
    float2 acc[16];
    #pragma unroll
    for (int j = 0; j < 16; ++j) acc[j] = make_float2(0.f, 0.f);
    for (int uu = 0; uu < CL; ++uu) {
        float2 wv = swv[uu][vd];
        #pragma unroll
        for (int j = 0; j < 16; ++j) {
            float2 kv = skk[uu][ks + (j << 2)];
            acc[j].x += wv.x * kv.x - wv.y * kv.y;
            acc[j].y += wv.x * kv.y + wv.y * kv.x;
        }
    }
    float2* out = Sc + ((size_t)(c * NH + h) << 12);
    #pragma unroll
    for (int j = 0; j < 16; ++j) out[vd * 64 + ks + (j << 2)] = acc[j];

    if (tid < 64) {
        float z = 0.f;
        #pragma unroll
        for (int uu = 0; uu < CL; ++uu) z += sgk[uu][tid];
        Zc[(c * NH + h) * 64 + tid] = z;
    }
}

// ---------------------------------------------------------------------------
// chunkscan: in-place exclusive prefix over chunks (elementwise, parallel)
// ---------------------------------------------------------------------------
__global__ __launch_bounds__(256) void chunkscan_kernel(
    const float* __restrict__ lgs, const float* __restrict__ lgz,
    const float* __restrict__ phs,
    float2* __restrict__ Sc, float* __restrict__ Zc)
{
    const int h = blockIdx.x;
    const int slice = blockIdx.y;
    if (slice < 16) {
        float xs = lgs[h];
        float sps = fmaxf(xs, 0.f) + log1pf(expf(-fabsf(xs)));
        float ph = phs[h];
        float r = expf(-sps * (float)CL);
        float2 aL = make_float2(r * cosf(ph * (float)CL), r * sinf(ph * (float)CL));
        int idx = slice * 256 + threadIdx.x;
        float2 prev = make_float2(0.f, 0.f);
        for (int c = 0; c < NC; ++c) {
            float2* p = Sc + ((size_t)(c * NH + h) << 12) + idx;
            float2 tmp = *p;
            *p = prev;
            prev = make_float2(aL.x * prev.x - aL.y * prev.y + tmp.x,
                               aL.x * prev.y + aL.y * prev.x + tmp.y);
        }
    } else if (threadIdx.x < 64) {
        float xz = lgz[h];
        float spz = fmaxf(xz, 0.f) + log1pf(expf(-fabsf(xz)));
        float azL = expf(-spz * (float)CL);
        float prev = 0.f;
        for (int c = 0; c < NC; ++c) {
            float* p = Zc + (c * NH + h) * 64 + threadIdx.x;
            float tmp = *p;
            *p = prev;
            prev = azL * prev + tmp;
        }
    }
}

// ---------------------------------------------------------------------------
// chunkout v2: intra scores + inter via LDS-staged Sp tile; writes Y2 as fp16.
// Phase A: scores sW + den (uses skkT/sgkT/sgq overlay region).
// Then: stage Sp into overlay (dead region), phase B intra, barrier, phase C.
// ---------------------------------------------------------------------------
__global__ __launch_bounds__(256) void chunkout_kernel(
    const float* __restrict__ F, const float* __restrict__ GQ, const float* __restrict__ GK,
    const float2* __restrict__ Sp, const float* __restrict__ Zp,
    const float* __restrict__ lgs, const float* __restrict__ lgz,
    const float* __restrict__ phs,
    _Float16* __restrict__ Y2h)
{
    __shared__ float2 sqf[CL][65];
    __shared__ float2 sv[CL][65];
    __shared__ float2 sW[CL][33];
    __shared__ float  sDinv[CL];
    __shared__ float  sZp[64];
    __shared__ float2 s_apow[CL + 1];
    __shared__ float  s_azpow[CL + 1];
    __shared__ char   ovl[33792];    // phase A: skkT[64][33]f2 | sgkT[64][33]f | sgq[32][65]f
                                     // phase C: sSp[64][66]f2
    float2* skkT = (float2*)ovl;
    float*  sgkT = (float*)(ovl + 16896);
    float*  sgq  = (float*)(ovl + 16896 + 8448);
    float2* sSp  = (float2*)ovl;

    const int tid = threadIdx.x;
    const int c = blockIdx.x & 63;
    const int h = blockIdx.x >> 6;

    if (tid <= CL) {
        float xs = lgs[h];
        float sps = fmaxf(xs, 0.f) + log1pf(expf(-fabsf(xs)));
        float ph = phs[h];
        float r = expf(-sps * (float)tid);
        s_apow[tid] = make_float2(r * cosf(ph * (float)tid), r * sinf(ph * (float)tid));
        float xz = lgz[h];
        float spz = fmaxf(xz, 0.f) + log1pf(expf(-fabsf(xz)));
        s_azpow[tid] = expf(-spz * (float)tid);
    }
    if (tid < 64) sZp[tid] = Zp[(c * NH + h) * 64 + tid];

    {
        const int u = tid >> 3, k0 = (tid & 7) << 3;
        const float* row = F + (size_t)(c * CL + u) * 3072 + h * HDD + k0;
        float qre[8], qim[8], kre[8], kim[8], vre[8], vim[8], gqv[8], gkv[8];
        *(float4*)(qre)     = *(const float4*)(row);
        *(float4*)(qre + 4) = *(const float4*)(row + 4);
        *(float4*)(qim)     = *(const float4*)(row + 512);
        *(float4*)(qim + 4) = *(const float4*)(row + 516);
        *(float4*)(kre)     = *(const float4*)(row + 1024);
        *(float4*)(kre + 4) = *(const float4*)(row + 1028);
        *(float4*)(kim)     = *(const float4*)(row + 1536);
        *(float4*)(kim + 4) = *(const float4*)(row + 1540);
        *(float4*)(vre)     = *(const float4*)(row + 2048);
        *(float4*)(vre + 4) = *(const float4*)(row + 2052);
        *(float4*)(vim)     = *(const float4*)(row + 2560);
        *(float4*)(vim + 4) = *(const float4*)(row + 2564);
        const float* gqrow = GQ + (size_t)(c * CL + u) * 512 + h * HDD + k0;
        const float* gkrow = GK + (size_t)(c * CL + u) * 512 + h * HDD + k0;
        *(float4*)(gqv)     = *(const float4*)(gqrow);
        *(float4*)(gqv + 4) = *(const float4*)(gqrow + 4);
        *(float4*)(gkv)     = *(const float4*)(gkrow);
        *(float4*)(gkv + 4) = *(const float4*)(gkrow + 4);
        #pragma unroll
        for (int i = 0; i < 8; ++i) {
            sqf[u][k0 + i]          = make_float2(qre[i], qim[i]);
            skkT[(k0 + i) * 33 + u] = make_float2(kre[i], kim[i]);
            sv[u][k0 + i]           = make_float2(vre[i], vim[i]);
            sgq[u * 65 + k0 + i]    = gqv[i];
            sgkT[(k0 + i) * 33 + u] = gkv[i];
        }
    }
    __syncthreads();

    // ---- phase A: score matrices, decay-mask, denominator ----
    {
        const int ta = tid >> 3, u4 = tid & 7;
        float2 A[4];
        float Ad[4] = {0.f, 0.f, 0.f, 0.f};
        #pragma unroll
        for (int j = 0; j < 4; ++j) A[j] = make_float2(0.f, 0.f);
        float zdot = 0.f;
        for (int k = 0; k < 64; ++k) {
            float2 q = sqf[ta][k];
            float g = sgq[ta * 65 + k];
            zdot += sZp[k] * g;
            #pragma unroll
            for (int j = 0; j < 4; ++j) {
                float2 kv = skkT[k * 33 + u4 + (j << 3)];
                A[j].x += q.x * kv.x - q.y * kv.y;
                A[j].y += q.x * kv.y + q.y * kv.x;
                Ad[j] += g * sgkT[k * 33 + u4 + (j << 3)];
            }
        }
        float denp = 0.f;
        #pragma unroll
        for (int j = 0; j < 4; ++j) {
            int uu = u4 + (j << 3);
            float2 wv = make_float2(0.f, 0.f);
            if (uu <= ta) {
                float2 p = s_apow[ta - uu];
                wv = cmul(p, A[j]);
                denp += s_azpow[ta - uu] * Ad[j];
            }
            sW[ta][uu] = wv;
        }
        denp += __shfl_xor(denp, 1);
        denp += __shfl_xor(denp, 2);
        denp += __shfl_xor(denp, 4);
        if (u4 == 0) {
            float den = denp + s_azpow[ta + 1] * zdot;
            sDinv[ta] = 1.f / (den + EPS_F);
        }
    }
    __syncthreads();   // phase A done; skkT/sgkT/sgq now dead

    // ---- stage Sp tile into overlay region (coalesced, 16 float2/thread) ----
    {
        const float2* gbase = Sp + ((size_t)(c * NH + h) << 12) + tid * 16;
        const int vd0 = tid >> 2;
        const int kk0 = (tid & 3) << 4;
        float2* dstp = sSp + vd0 * 66 + kk0;
        #pragma unroll
        for (int i = 0; i < 8; ++i) {
            float4 d = *(const float4*)(gbase + 2 * i);
            *(float4*)(dstp + 2 * i) = d;
        }
    }

    // ---- phase B: intra num = W @ V (reads sW, sv only) ----
    const int t = tid >> 3, vs = tid & 7;
    float2 acc[8];
    #pragma unroll
    for (int j = 0; j < 8; ++j) acc[j] = make_float2(0.f, 0.f);
    for (int uu = 0; uu < CL; ++uu) {
        float2 w = sW[t][uu];
        #pragma unroll
        for (int j = 0; j < 8; ++j) {
            float2 vv = sv[uu][vs + (j << 3)];
            acc[j].x += w.x * vv.x - w.y * vv.y;
            acc[j].y += w.x * vv.y + w.y * vv.x;
        }
    }
    __syncthreads();   // sSp staged & visible

    // ---- phase C: inter num += apow[t+1] * (Sp @ qf) ----
    {
        float2 bacc[8];
        #pragma unroll
        for (int j = 0; j < 8; ++j) bacc[j] = make_float2(0.f, 0.f);
        for (int k = 0; k < 64; ++k) {
            float2 q = sqf[t][k];
            #pragma unroll
            for (int j = 0; j < 8; ++j) {
                float2 s = sSp[(vs + (j << 3)) * 66 + k];
                bacc[j].x += s.x * q.x - s.y * q.y;
                bacc[j].y += s.x * q.y + s.y * q.x;
            }
        }
        const float2 fac = s_apow[t + 1];
        const float dinv = sDinv[t];
        _Float16* orow = Y2h + (size_t)(c * CL + t) * 1024 + h * HDD;
        #pragma unroll
        for (int j = 0; j < 8; ++j) {
            float rx = acc[j].x + fac.x * bacc[j].x - fac.y * bacc[j].y;
            float ry = acc[j].y + fac.x * bacc[j].y + fac.y * bacc[j].x;
            int vdd = vs + (j << 3);
            orow[vdd]       = (_Float16)(rx * dinv);
            orow[512 + vdd] = (_Float16)(ry * dinv);
        }
    }
}

// ---------------------------------------------------------------------------
extern "C" void kernel_launch(void* const* d_in, const int* in_sizes, int n_in,
                              void* d_out, int out_size, void* d_ws, size_t ws_size,
                              hipStream_t stream)
{
    const float* x    = (const float*)d_in[0];
    const float* q_wr = (const float*)d_in[1];
    const float* q_wi = (const float*)d_in[2];
    const float* q_br = (const float*)d_in[3];
    const float* q_bi = (const float*)d_in[4];
    const float* k_wr = (const float*)d_in[5];
    const float* k_wi = (const float*)d_in[6];
    const float* k_br = (const float*)d_in[7];
    const float* k_bi = (const float*)d_in[8];
    const float* v_wr = (const float*)d_in[9];
    const float* v_wi = (const float*)d_in[10];
    const float* v_br = (const float*)d_in[11];
    const float* v_bi = (const float*)d_in[12];
    const float* o_wr = (const float*)d_in[13];
    const float* o_wi = (const float*)d_in[14];
    const float* o_br = (const float*)d_in[15];
    const float* o_bi = (const float*)d_in[16];
    const float* log_decay_s = (const float*)d_in[17];
    const float* log_decay_z = (const float*)d_in[18];
    const float* phase       = (const float*)d_in[19];

    float* ws = (float*)d_ws;
    float* Y1   = ws;                    // 6291456
    float* gq   = ws + 6291456;          // 1048576
    float* gk   = ws + 7340032;          // 1048576
    float* Scf  = ws + 8388608;          // 4194304
    float* Zcf  = ws + 12582912;         // 32768
    float* ball = ws + 12615680;         // 3072
    float* b2a  = ws + 12618752;         // 1024
    _Float16* Xh  = (_Float16*)(ws + 12619776);   // 1048576 halves
    _Float16* WTa = Xh + 1048576;                 // 1572864
    _Float16* W2T = WTa + 1572864;                // 1048576
    _Float16* Y2h = W2T + 1048576;                // 2097152

    int out_mode = (out_size == 2048 * 1024) ? 1 : 0;

    xconv_kernel<<<1024, 256, 0, stream>>>(x, Xh);
    biasprep_kernel<<<16, 256, 0, stream>>>(q_br, q_bi, k_br, k_bi, v_br, v_bi,
                                            o_br, o_bi, ball, b2a);
    wconv_kernel<<<dim3(8, 8, 6), 256, 0, stream>>>(q_wr, q_wi, k_wr, k_wi, v_wr, v_wi, WTa);
    w2prep_kernel<<<dim3(16, 16), 256, 0, stream>>>(o_wr, o_wi, W2T);

    // GEMM1: Y1[2048][3072] = Xh @ WTa^T + ball
    gemm_f16_kernel<<<dim3(24, 16), 256, 0, stream>>>(Xh, WTa, ball, Y1, 512, 3072, 0);

    feature_kernel<<<4096, 256, 0, stream>>>(Y1, gq, gk);

    chunkstate_kernel<<<512, 256, 0, stream>>>(Y1, gk, log_decay_s, log_decay_z, phase,
                                               (float2*)Scf, Zcf);

    chunkscan_kernel<<<dim3(8, 17), 256, 0, stream>>>(log_decay_s, log_decay_z, phase,
                                                      (float2*)Scf, Zcf);

    chunkout_kernel<<<512, 256, 0, stream>>>(Y1, gq, gk, (const float2*)Scf, Zcf,
                                             log_decay_s, log_decay_z, phase, Y2h);

    // GEMM2: out = Y2h @ W2T^T + b2a
    if (out_mode == 1) {
        gemm_f16_kernel<<<dim3(8, 16), 256, 0, stream>>>(Y2h, W2T, b2a, (float*)d_out,
                                                         1024, 1024, 1);
    } else {
        gemm_f16_kernel<<<dim3(4, 16), 256, 0, stream>>>(Y2h, W2T, b2a, (float*)d_out,
                                                         1024, 512, 0);
    }
}

// Round 4
// 92.249 us; speedup vs baseline: 15.1780x; 1.8160x over previous
//
#include <hip/hip_runtime.h>
#include <math.h>

#define TT 2048
#define NH 8
#define HDD 64
#define CL 32          // chunk length
#define NC 64          // number of chunks
#define EPS_F 1e-8f

typedef __attribute__((ext_vector_type(8))) _Float16 half8;
typedef __attribute__((ext_vector_type(4))) _Float16 half4;
typedef __attribute__((ext_vector_type(4))) float    f32x4;

__device__ __forceinline__ float2 cmul(float2 a, float2 b) {
    return make_float2(a.x*b.x - a.y*b.y, a.x*b.y + a.y*b.x);
}
__device__ __forceinline__ half8 cvt8(const float* p) {
    float4 a = *(const float4*)p, b = *(const float4*)(p + 4);
    half8 r;
    r[0]=(_Float16)a.x; r[1]=(_Float16)a.y; r[2]=(_Float16)a.z; r[3]=(_Float16)a.w;
    r[4]=(_Float16)b.x; r[5]=(_Float16)b.y; r[6]=(_Float16)b.z; r[7]=(_Float16)b.w;
    return r;
}
__device__ __forceinline__ half8 neg8(half8 v) {
    half8 r;
    #pragma unroll
    for (int i = 0; i < 8; ++i) r[i] = -v[i];
    return r;
}

// ---------------------------------------------------------------------------
// xconv: fp32 -> fp16, 4 elems/thread
// ---------------------------------------------------------------------------
__global__ void xconv_kernel(const float* __restrict__ X, _Float16* __restrict__ Xh)
{
    int i4 = blockIdx.x * 256 + threadIdx.x;
    float4 v = ((const float4*)X)[i4];
    half4 o;
    o[0] = (_Float16)v.x; o[1] = (_Float16)v.y;
    o[2] = (_Float16)v.z; o[3] = (_Float16)v.w;
    ((half4*)Xh)[i4] = o;
}

// ---------------------------------------------------------------------------
// biasprep
// ---------------------------------------------------------------------------
__global__ void biasprep_kernel(
    const float* __restrict__ bq_r, const float* __restrict__ bq_i,
    const float* __restrict__ bk_r, const float* __restrict__ bk_i,
    const float* __restrict__ bv_r, const float* __restrict__ bv_i,
    const float* __restrict__ o_br, const float* __restrict__ o_bi,
    float* __restrict__ ball, float* __restrict__ b2a)
{
    int idx = blockIdx.x * 256 + threadIdx.x;   // 0..4095
    if (idx < 3072) {
        int grp = idx >> 9, d = idx & 511;
        float v;
        switch (grp) {
          case 0: v = bq_r[d]; break;
          case 1: v = bq_i[d]; break;
          case 2: v = bk_r[d]; break;
          case 3: v = bk_i[d]; break;
          case 4: v = bv_r[d]; break;
          default: v = bv_i[d]; break;
        }
        ball[idx] = v;
    } else {
        int j = idx - 3072;
        b2a[j] = (j < 512) ? o_br[j] : o_bi[j - 512];
    }
}

// ---------------------------------------------------------------------------
// wconv: transpose-convert projection weights into WT_all [3072][512] fp16
// ---------------------------------------------------------------------------
__global__ __launch_bounds__(256) void wconv_kernel(
    const float* __restrict__ Wq_r, const float* __restrict__ Wq_i,
    const float* __restrict__ Wk_r, const float* __restrict__ Wk_i,
    const float* __restrict__ Wv_r, const float* __restrict__ Wv_i,
    _Float16* __restrict__ WT)
{
    __shared__ float tile[64][65];
    const int tid = threadIdx.x;
    const int k0 = blockIdx.x * 64, n0 = blockIdx.y * 64, g = blockIdx.z;
    const float* W;
    switch (g) {
      case 0: W = Wq_r; break;
      case 1: W = Wq_i; break;
      case 2: W = Wk_r; break;
      case 3: W = Wk_i; break;
      case 4: W = Wv_r; break;
      default: W = Wv_i; break;
    }
    #pragma unroll
    for (int it = 0; it < 16; ++it) {
        int idx = it * 256 + tid;
        tile[idx >> 6][idx & 63] = W[(size_t)(k0 + (idx >> 6)) * 512 + n0 + (idx & 63)];
    }
    __syncthreads();
    #pragma unroll
    for (int it = 0; it < 16; ++it) {
        int idx = it * 256 + tid;
        int nr = idx >> 6, kc = idx & 63;
        WT[(size_t)(g * 512 + n0 + nr) * 512 + k0 + kc] = (_Float16)tile[kc][nr];
    }
}

// ---------------------------------------------------------------------------
// w2prep: combined real output-projection weight, transposed + fp16
// ---------------------------------------------------------------------------
__global__ __launch_bounds__(256) void w2prep_kernel(
    const float* __restrict__ o_wr, const float* __restrict__ o_wi,
    _Float16* __restrict__ W2T)
{
    __shared__ float tile[64][65];
    const int tid = threadIdx.x;
    const int i0 = blockIdx.x * 64, j0 = blockIdx.y * 64;
    const float* src; float sgn; int io, jo;
    if (i0 < 512) {
        if (j0 < 512) { src = o_wr; sgn = 1.f;  io = i0; jo = j0; }
        else          { src = o_wi; sgn = 1.f;  io = i0; jo = j0 - 512; }
    } else {
        if (j0 < 512) { src = o_wi; sgn = -1.f; io = i0 - 512; jo = j0; }
        else          { src = o_wr; sgn = 1.f;  io = i0 - 512; jo = j0 - 512; }
    }
    #pragma unroll
    for (int it = 0; it < 16; ++it) {
        int idx = it * 256 + tid;
        tile[idx >> 6][idx & 63] = sgn * src[(size_t)(io + (idx >> 6)) * 512 + jo + (idx & 63)];
    }
    __syncthreads();
    #pragma unroll
    for (int it = 0; it < 16; ++it) {
        int idx = it * 256 + tid;
        int nr = idx >> 6, kc = idx & 63;
        W2T[(size_t)(j0 + nr) * 1024 + i0 + kc] = (_Float16)tile[kc][nr];
    }
}

// ---------------------------------------------------------------------------
// MFMA fp16 GEMM (unchanged from round 3)
// ---------------------------------------------------------------------------
__global__ __launch_bounds__(256) void gemm_f16_kernel(
    const _Float16* __restrict__ A,
    const _Float16* __restrict__ BT,
    const float* __restrict__ bias,
    float* __restrict__ C,
    int K, int ldc, int wmode)
{
    __shared__ _Float16 sA[128 * 32];
    __shared__ _Float16 sB[128 * 32];
    const int tid = threadIdx.x;
    const int m0 = blockIdx.y * 128, n0 = blockIdx.x * 128;
    const int lane = tid & 63;
    const int w = tid >> 6, wm = w >> 1, wn = w & 1;

    f32x4 acc[4][4];
    #pragma unroll
    for (int i = 0; i < 4; ++i)
        #pragma unroll
        for (int j = 0; j < 4; ++j) { f32x4 z = {0.f, 0.f, 0.f, 0.f}; acc[i][j] = z; }

    const int r0 = tid >> 2, r1 = (tid >> 2) + 64;
    const int sq = tid & 3;
    const _Float16* gA0 = A + (size_t)(m0 + r0) * K + (sq ^ ((r0 >> 1) & 3)) * 8;
    const _Float16* gA1 = A + (size_t)(m0 + r1) * K + (sq ^ ((r1 >> 1) & 3)) * 8;
    const _Float16* gB0 = BT + (size_t)(n0 + r0) * K + (sq ^ ((r0 >> 1) & 3)) * 8;
    const _Float16* gB1 = BT + (size_t)(n0 + r1) * K + (sq ^ ((r1 >> 1) & 3)) * 8;
    _Float16* wA0 = &sA[r0 * 32 + sq * 8];
    _Float16* wA1 = &sA[r1 * 32 + sq * 8];
    _Float16* wB0 = &sB[r0 * 32 + sq * 8];
    _Float16* wB1 = &sB[r1 * 32 + sq * 8];

    float4 pa0 = *(const float4*)gA0, pa1 = *(const float4*)gA1;
    float4 pb0 = *(const float4*)gB0, pb1 = *(const float4*)gB1;

    const int arow = wm * 64 + (lane & 15);
    const int brow = wn * 64 + (lane & 15);
    const int nsteps = K >> 5;

    for (int ks = 0; ks < nsteps; ++ks) {
        *(float4*)wA0 = pa0; *(float4*)wA1 = pa1;
        *(float4*)wB0 = pb0; *(float4*)wB1 = pb1;
        __syncthreads();
        if (ks + 1 < nsteps) {
            int ko = (ks + 1) << 5;
            pa0 = *(const float4*)(gA0 + ko); pa1 = *(const float4*)(gA1 + ko);
            pb0 = *(const float4*)(gB0 + ko); pb1 = *(const float4*)(gB1 + ko);
        }
        half8 af[4], bf[4];
        #pragma unroll
        for (int mt = 0; mt < 4; ++mt) {
            int r = arow + mt * 16;
            int qp = (lane >> 4) ^ ((r >> 1) & 3);
            af[mt] = *(half8*)&sA[r * 32 + qp * 8];
        }
        #pragma unroll
        for (int nt = 0; nt < 4; ++nt) {
            int r = brow + nt * 16;
            int qp = (lane >> 4) ^ ((r >> 1) & 3);
            bf[nt] = *(half8*)&sB[r * 32 + qp * 8];
        }
        #pragma unroll
        for (int mt = 0; mt < 4; ++mt)
            #pragma unroll
            for (int nt = 0; nt < 4; ++nt)
                acc[mt][nt] = __builtin_amdgcn_mfma_f32_16x16x32_f16(af[mt], bf[nt], acc[mt][nt], 0, 0, 0);
        __syncthreads();
    }

    const int crow0 = m0 + wm * 64 + (lane >> 4) * 4;
    const int ccol0 = n0 + wn * 64 + (lane & 15);
    #pragma unroll
    for (int mt = 0; mt < 4; ++mt) {
        #pragma unroll
        for (int nt = 0; nt < 4; ++nt) {
            int col = ccol0 + nt * 16;
            float b = bias[col];
            #pragma unroll
            for (int rg = 0; rg < 4; ++rg) {
                int row = crow0 + mt * 16 + rg;
                float val = acc[mt][nt][rg] + b;
                if (wmode == 0) {
                    C[(size_t)row * ldc + col] = val;
                } else {
                    int off = (col < 512) ? (row * 1024 + 2 * col) : (row * 1024 + 2 * (col - 512) + 1);
                    C[off] = val;
                }
            }
        }
    }
}

// ---------------------------------------------------------------------------
// Features (in place on Y1)
// ---------------------------------------------------------------------------
__global__ void feature_kernel(float* __restrict__ Y1,
                               float* __restrict__ gq_arr, float* __restrict__ gk_arr)
{
    int idx = blockIdx.x * 256 + threadIdx.x;
    int t = idx >> 9, d = idx & 511;
    float* row = Y1 + t * 3072;
    float qr = row[d], qi = row[512 + d];
    float g = sqrtf(qr * qr + qi * qi);
    float f = g / (g + EPS_F);
    row[d] = qr * f; row[512 + d] = qi * f;
    gq_arr[idx] = g;
    float kr = row[1024 + d], ki = row[1536 + d];
    g = sqrtf(kr * kr + ki * ki);
    f = g / (g + EPS_F);
    row[1024 + d] = kr * f; row[1536 + d] = -ki * f;   // conj
    gk_arr[idx] = g;
}

// ---------------------------------------------------------------------------
// chunkstate v2 (MFMA): Sc[vd][k] = sum_u (apow[31-u]*v[u])[vd] * kk[u][k]
//                       Zc[k]     = sum_u azpow[31-u] * gk[u][k]
// grid 512 = 64 chunks x 8 heads, 256 threads (4 waves)
// ---------------------------------------------------------------------------
__global__ __launch_bounds__(256) void chunkstate_kernel(
    const float* __restrict__ F, const float* __restrict__ GK,
    const float* __restrict__ lgs, const float* __restrict__ lgz,
    const float* __restrict__ phs,
    float2* __restrict__ Sc, float* __restrict__ Zc)
{
    __shared__ _Float16 wvTr[64 * 40], wvTi[64 * 40];          // [vd][u]
    __shared__ _Float16 kkTr[64 * 40], kkTi[64 * 40], kkTiN[64 * 40];  // [k][u]
    __shared__ float    Lgkz[32 * 65];                         // [u][k] weighted

    const int tid = threadIdx.x;
    const int c = blockIdx.x & 63, h = blockIdx.x >> 6;

    // per-thread decay for staging weights
    float xs = lgs[h];
    float sps = fmaxf(xs, 0.f) + log1pf(expf(-fabsf(xs)));
    float ph = phs[h];
    float xz = lgz[h];
    float spz = fmaxf(xz, 0.f) + log1pf(expf(-fabsf(xz)));

    {
        const int u = tid >> 3, ks = (tid & 7) << 3;
        const float* row = F + (size_t)(c * CL + u) * 3072 + h * HDD + ks;
        float kre[8], kim[8], vre[8], vim[8], gkv[8];
        *(float4*)(kre)     = *(const float4*)(row + 1024);
        *(float4*)(kre + 4) = *(const float4*)(row + 1028);
        *(float4*)(kim)     = *(const float4*)(row + 1536);
        *(float4*)(kim + 4) = *(const float4*)(row + 1540);
        *(float4*)(vre)     = *(const float4*)(row + 2048);
        *(float4*)(vre + 4) = *(const float4*)(row + 2052);
        *(float4*)(vim)     = *(const float4*)(row + 2560);
        *(float4*)(vim + 4) = *(const float4*)(row + 2564);
        const float* grow = GK + (size_t)(c * CL + u) * 512 + h * HDD + ks;
        *(float4*)(gkv)     = *(const float4*)(grow);
        *(float4*)(gkv + 4) = *(const float4*)(grow + 4);
        float e = (float)(CL - 1 - u);
        float r = expf(-sps * e);
        float2 wA = make_float2(r * cosf(ph * e), r * sinf(ph * e));
        float wz = expf(-spz * e);
        #pragma unroll
        for (int j = 0; j < 8; ++j) {
            int kcol = ks + j;
            kkTr[kcol * 40 + u]  = (_Float16)kre[j];
            kkTi[kcol * 40 + u]  = (_Float16)kim[j];
            kkTiN[kcol * 40 + u] = (_Float16)(-kim[j]);
            float wr = wA.x * vre[j] - wA.y * vim[j];
            float wi = wA.x * vim[j] + wA.y * vre[j];
            wvTr[kcol * 40 + u] = (_Float16)wr;
            wvTi[kcol * 40 + u] = (_Float16)wi;
            Lgkz[u * 65 + kcol] = wz * gkv[j];
        }
    }
    __syncthreads();

    const int w = tid >> 6, lane = tid & 63;
    const int quad = lane >> 4, l15 = lane & 15;
    const int arow = (w * 16 + l15) * 40 + quad * 8;
    half8 fvr = *(const half8*)&wvTr[arow];
    half8 fvi = *(const half8*)&wvTi[arow];
    float2* out = Sc + ((size_t)(c * NH + h) << 12);
    #pragma unroll
    for (int kq = 0; kq < 4; ++kq) {
        int brow = (kq * 16 + l15) * 40 + quad * 8;
        half8 fkr  = *(const half8*)&kkTr[brow];
        half8 fki  = *(const half8*)&kkTi[brow];
        half8 fkiN = *(const half8*)&kkTiN[brow];
        f32x4 Cr = {0.f, 0.f, 0.f, 0.f}, Ci = {0.f, 0.f, 0.f, 0.f};
        Cr = __builtin_amdgcn_mfma_f32_16x16x32_f16(fvr, fkr,  Cr, 0, 0, 0);
        Cr = __builtin_amdgcn_mfma_f32_16x16x32_f16(fvi, fkiN, Cr, 0, 0, 0);
        Ci = __builtin_amdgcn_mfma_f32_16x16x32_f16(fvr, fki,  Ci, 0, 0, 0);
        Ci = __builtin_amdgcn_mfma_f32_16x16x32_f16(fvi, fkr,  Ci, 0, 0, 0);
        #pragma unroll
        for (int reg = 0; reg < 4; ++reg) {
            int vd = w * 16 + quad * 4 + reg;
            out[(size_t)vd * 64 + kq * 16 + l15] = make_float2(Cr[reg], Ci[reg]);
        }
    }
    if (tid < 64) {
        float z = 0.f;
        #pragma unroll
        for (int uu = 0; uu < 32; ++uu) z += Lgkz[uu * 65 + tid];
        Zc[(c * NH + h) * 64 + tid] = z;
    }
}

// ---------------------------------------------------------------------------
// chunkscan (unchanged): exclusive prefix over chunks
// ---------------------------------------------------------------------------
__global__ __launch_bounds__(256) void chunkscan_kernel(
    const float* __restrict__ lgs, const float* __restrict__ lgz,
    const float* __restrict__ phs,
    float2* __restrict__ Sc, float* __restrict__ Zc)
{
    const int h = blockIdx.x;
    const int slice = blockIdx.y;
    if (slice < 16) {
        float xs = lgs[h];
        float sps = fmaxf(xs, 0.f) + log1pf(expf(-fabsf(xs)));
        float ph = phs[h];
        float r = expf(-sps * (float)CL);
        float2 aL = make_float2(r * cosf(ph * (float)CL), r * sinf(ph * (float)CL));
        int idx = slice * 256 + threadIdx.x;
        float2 prev = make_float2(0.f, 0.f);
        for (int c = 0; c < NC; ++c) {
            float2* p = Sc + ((size_t)(c * NH + h) << 12) + idx;
            float2 tmp = *p;
            *p = prev;
            prev = make_float2(aL.x * prev.x - aL.y * prev.y + tmp.x,
                               aL.x * prev.y + aL.y * prev.x + tmp.y);
        }
    } else if (threadIdx.x < 64) {
        float xz = lgz[h];
        float spz = fmaxf(xz, 0.f) + log1pf(expf(-fabsf(xz)));
        float azL = expf(-spz * (float)CL);
        float prev = 0.f;
        for (int c = 0; c < NC; ++c) {
            float* p = Zc + (c * NH + h) * 64 + threadIdx.x;
            float tmp = *p;
            *p = prev;
            prev = azL * prev + tmp;
        }
    }
}

// ---------------------------------------------------------------------------
// chunkout v3 (MFMA): scores+den -> masked sW; inter = Sp@qf; intra = vT@sW^T;
// combine in registers, write Y2 fp16.  grid 512, 256 threads (4 waves).
// ---------------------------------------------------------------------------
__global__ __launch_bounds__(256) void chunkout_kernel(
    const float* __restrict__ F, const float* __restrict__ GQ, const float* __restrict__ GK,
    const float2* __restrict__ Sp, const float* __restrict__ Zp,
    const float* __restrict__ lgs, const float* __restrict__ lgz,
    const float* __restrict__ phs,
    _Float16* __restrict__ Y2h)
{
    __shared__ _Float16 Lqr[32 * 72], Lqi[32 * 72], LqiN[32 * 72];   // [t][k]
    __shared__ _Float16 Lkr[32 * 72], Lki[32 * 72], LkiN[32 * 72];   // [u][k]
    __shared__ _Float16 Lgq[32 * 72], Lgk[32 * 72];
    __shared__ _Float16 Spr[64 * 72], Spi[64 * 72];                  // [vd][k]
    __shared__ _Float16 Vtr[64 * 40], Vti[64 * 40];                  // [vd][u]
    __shared__ _Float16 Wr_[32 * 32], Wi_[32 * 32], WiN[32 * 32];    // [t][u]
    __shared__ float  sDenP[2][32], sZdot[32], sDinv[32], sZp[64];
    __shared__ float2 s_apow[CL + 1];
    __shared__ float  s_azpow[CL + 1];

    const int tid = threadIdx.x;
    const int c = blockIdx.x & 63, h = blockIdx.x >> 6;

    if (tid <= CL) {
        float xs = lgs[h];
        float sps = fmaxf(xs, 0.f) + log1pf(expf(-fabsf(xs)));
        float ph = phs[h];
        float r = expf(-sps * (float)tid);
        s_apow[tid] = make_float2(r * cosf(ph * (float)tid), r * sinf(ph * (float)tid));
        float xz = lgz[h];
        float spz = fmaxf(xz, 0.f) + log1pf(expf(-fabsf(xz)));
        s_azpow[tid] = expf(-spz * (float)tid);
    }
    if (tid < 64) sZp[tid] = Zp[(c * NH + h) * 64 + tid];

    // ---- staging: features -> fp16 planes ----
    {
        const int u = tid >> 3, ks = (tid & 7) << 3;
        const float* row = F + (size_t)(c * CL + u) * 3072 + h * HDD + ks;
        half8 qr = cvt8(row),        qi = cvt8(row + 512);
        half8 kr = cvt8(row + 1024), ki = cvt8(row + 1536);
        half8 vr8 = cvt8(row + 2048), vi8 = cvt8(row + 2560);
        half8 g8q = cvt8(GQ + (size_t)(c * CL + u) * 512 + h * HDD + ks);
        half8 g8k = cvt8(GK + (size_t)(c * CL + u) * 512 + h * HDD + ks);
        int ofs = u * 72 + ks;
        *(half8*)&Lqr[ofs] = qr;  *(half8*)&Lqi[ofs] = qi;  *(half8*)&LqiN[ofs] = neg8(qi);
        *(half8*)&Lkr[ofs] = kr;  *(half8*)&Lki[ofs] = ki;  *(half8*)&LkiN[ofs] = neg8(ki);
        *(half8*)&Lgq[ofs] = g8q; *(half8*)&Lgk[ofs] = g8k;
        #pragma unroll
        for (int j = 0; j < 8; ++j) {
            Vtr[(ks + j) * 40 + u] = vr8[j];
            Vti[(ks + j) * 40 + u] = vi8[j];
        }
    }
    // ---- staging: Sp fp32 complex -> fp16 planes ----
    {
        const int vd = tid >> 2, k0 = (tid & 3) << 4;
        const float4* g4 = (const float4*)(Sp + ((size_t)(c * NH + h) << 12) + vd * 64 + k0);
        half8 pr[2], pi[2];
        #pragma unroll
        for (int half = 0; half < 2; ++half) {
            #pragma unroll
            for (int j = 0; j < 4; ++j) {
                float4 s = g4[half * 4 + j];
                pr[half][2*j]   = (_Float16)s.x; pi[half][2*j]   = (_Float16)s.y;
                pr[half][2*j+1] = (_Float16)s.z; pi[half][2*j+1] = (_Float16)s.w;
            }
        }
        int ofs = vd * 72 + k0;
        *(half8*)&Spr[ofs]     = pr[0]; *(half8*)&Spr[ofs + 8] = pr[1];
        *(half8*)&Spi[ofs]     = pi[0]; *(half8*)&Spi[ofs + 8] = pi[1];
    }
    __syncthreads();

    // ---- zdot[t] = Zp . gq[t] (VALU) ----
    {
        const int t = tid >> 3, k8 = (tid & 7) << 3;
        float z = 0.f;
        #pragma unroll
        for (int j = 0; j < 8; ++j) z += sZp[k8 + j] * (float)Lgq[t * 72 + k8 + j];
        z += __shfl_xor(z, 1); z += __shfl_xor(z, 2); z += __shfl_xor(z, 4);
        if ((tid & 7) == 0) sZdot[t] = z;
    }

    const int w = tid >> 6, lane = tid & 63;
    const int quad = lane >> 4, l15 = lane & 15;
    const int th = w >> 1, uh = w & 1;
    const f32x4 zero = {0.f, 0.f, 0.f, 0.f};

    // ---- phase 1a: scores + den MFMA (wave tile (th, uh)) ----
    f32x4 Ar = zero, Ai = zero, Dn = zero;
    {
        const int qrow = (th * 16 + l15) * 72;
        const int krow = (uh * 16 + l15) * 72;
        #pragma unroll
        for (int s = 0; s < 2; ++s) {
            int ko = s * 32 + quad * 8;
            half8 fqr  = *(const half8*)&Lqr[qrow + ko];
            half8 fqi  = *(const half8*)&Lqi[qrow + ko];
            half8 fkr  = *(const half8*)&Lkr[krow + ko];
            half8 fki  = *(const half8*)&Lki[krow + ko];
            half8 fkiN = *(const half8*)&LkiN[krow + ko];
            Ar = __builtin_amdgcn_mfma_f32_16x16x32_f16(fqr, fkr,  Ar, 0, 0, 0);
            Ar = __builtin_amdgcn_mfma_f32_16x16x32_f16(fqi, fkiN, Ar, 0, 0, 0);
            Ai = __builtin_amdgcn_mfma_f32_16x16x32_f16(fqr, fki,  Ai, 0, 0, 0);
            Ai = __builtin_amdgcn_mfma_f32_16x16x32_f16(fqi, fkr,  Ai, 0, 0, 0);
            half8 fgq = *(const half8*)&Lgq[qrow + ko];
            half8 fgk = *(const half8*)&Lgk[krow + ko];
            Dn = __builtin_amdgcn_mfma_f32_16x16x32_f16(fgq, fgk, Dn, 0, 0, 0);
        }
    }
    // ---- phase 1b: inter = Sp @ qf (wave owns vd quarter w, both t halves) ----
    f32x4 IRr[2] = {zero, zero}, IRi[2] = {zero, zero};
    {
        const int prow = (w * 16 + l15) * 72;
        #pragma unroll
        for (int s = 0; s < 2; ++s) {
            int ko = s * 32 + quad * 8;
            half8 fSr = *(const half8*)&Spr[prow + ko];
            half8 fSi = *(const half8*)&Spi[prow + ko];
            #pragma unroll
            for (int t2 = 0; t2 < 2; ++t2) {
                int qrow = (t2 * 16 + l15) * 72 + ko;
                half8 fqr  = *(const half8*)&Lqr[qrow];
                half8 fqi  = *(const half8*)&Lqi[qrow];
                half8 fqiN = *(const half8*)&LqiN[qrow];
                IRr[t2] = __builtin_amdgcn_mfma_f32_16x16x32_f16(fSr, fqr,  IRr[t2], 0, 0, 0);
                IRr[t2] = __builtin_amdgcn_mfma_f32_16x16x32_f16(fSi, fqiN, IRr[t2], 0, 0, 0);
                IRi[t2] = __builtin_amdgcn_mfma_f32_16x16x32_f16(fSr, fqi,  IRi[t2], 0, 0, 0);
                IRi[t2] = __builtin_amdgcn_mfma_f32_16x16x32_f16(fSi, fqr,  IRi[t2], 0, 0, 0);
            }
        }
    }
    // ---- mask + decay scores -> sW planes; den partials ----
    #pragma unroll
    for (int reg = 0; reg < 4; ++reg) {
        int t = th * 16 + quad * 4 + reg;
        int u = uh * 16 + l15;
        float wr = 0.f, wi = 0.f, dd = 0.f;
        if (u <= t) {
            float2 p = s_apow[t - u];
            wr = p.x * Ar[reg] - p.y * Ai[reg];
            wi = p.x * Ai[reg] + p.y * Ar[reg];
            dd = s_azpow[t - u] * Dn[reg];
        }
        Wr_[t * 32 + u] = (_Float16)wr;
        Wi_[t * 32 + u] = (_Float16)wi;
        WiN[t * 32 + u] = (_Float16)(-wi);
        dd += __shfl_xor(dd, 1); dd += __shfl_xor(dd, 2);
        dd += __shfl_xor(dd, 4); dd += __shfl_xor(dd, 8);
        if (l15 == 0) sDenP[uh][t] = dd;
    }
    __syncthreads();

    if (tid < 32) {
        float den = sDenP[0][tid] + sDenP[1][tid] + s_azpow[tid + 1] * sZdot[tid];
        sDinv[tid] = 1.f / (den + EPS_F);
    }

    // ---- phase 2: intra = vT @ sW^T ----
    f32x4 NRr[2] = {zero, zero}, NRi[2] = {zero, zero};
    {
        const int vrow = (w * 16 + l15) * 40 + quad * 8;
        half8 fvr = *(const half8*)&Vtr[vrow];
        half8 fvi = *(const half8*)&Vti[vrow];
        #pragma unroll
        for (int t2 = 0; t2 < 2; ++t2) {
            int trow = (t2 * 16 + l15) * 32 + quad * 8;
            half8 fWr  = *(const half8*)&Wr_[trow];
            half8 fWi  = *(const half8*)&Wi_[trow];
            half8 fWiN = *(const half8*)&WiN[trow];
            NRr[t2] = __builtin_amdgcn_mfma_f32_16x16x32_f16(fvr, fWr,  NRr[t2], 0, 0, 0);
            NRr[t2] = __builtin_amdgcn_mfma_f32_16x16x32_f16(fvi, fWiN, NRr[t2], 0, 0, 0);
            NRi[t2] = __builtin_amdgcn_mfma_f32_16x16x32_f16(fvr, fWi,  NRi[t2], 0, 0, 0);
            NRi[t2] = __builtin_amdgcn_mfma_f32_16x16x32_f16(fvi, fWr,  NRi[t2], 0, 0, 0);
        }
    }
    __syncthreads();   // sDinv visible

    // ---- epilogue: combine + write ----
    #pragma unroll
    for (int t2 = 0; t2 < 2; ++t2) {
        int t = t2 * 16 + l15;
        float2 fac = s_apow[t + 1];
        float dinv = sDinv[t];
        half4 hre, him;
        #pragma unroll
        for (int reg = 0; reg < 4; ++reg) {
            float rx = NRr[t2][reg] + fac.x * IRr[t2][reg] - fac.y * IRi[t2][reg];
            float ry = NRi[t2][reg] + fac.x * IRi[t2][reg] + fac.y * IRr[t2][reg];
            hre[reg] = (_Float16)(rx * dinv);
            him[reg] = (_Float16)(ry * dinv);
        }
        int vd0 = w * 16 + quad * 4;
        _Float16* orow = Y2h + (size_t)(c * CL + t) * 1024 + h * HDD;
        *(half4*)&orow[vd0]       = hre;
        *(half4*)&orow[512 + vd0] = him;
    }
}

// ---------------------------------------------------------------------------
extern "C" void kernel_launch(void* const* d_in, const int* in_sizes, int n_in,
                              void* d_out, int out_size, void* d_ws, size_t ws_size,
                              hipStream_t stream)
{
    const float* x    = (const float*)d_in[0];
    const float* q_wr = (const float*)d_in[1];
    const float* q_wi = (const float*)d_in[2];
    const float* q_br = (const float*)d_in[3];
    const float* q_bi = (const float*)d_in[4];
    const float* k_wr = (const float*)d_in[5];
    const float* k_wi = (const float*)d_in[6];
    const float* k_br = (const float*)d_in[7];
    const float* k_bi = (const float*)d_in[8];
    const float* v_wr = (const float*)d_in[9];
    const float* v_wi = (const float*)d_in[10];
    const float* v_br = (const float*)d_in[11];
    const float* v_bi = (const float*)d_in[12];
    const float* o_wr = (const float*)d_in[13];
    const float* o_wi = (const float*)d_in[14];
    const float* o_br = (const float*)d_in[15];
    const float* o_bi = (const float*)d_in[16];
    const float* log_decay_s = (const float*)d_in[17];
    const float* log_decay_z = (const float*)d_in[18];
    const float* phase       = (const float*)d_in[19];

    float* ws = (float*)d_ws;
    float* Y1   = ws;                    // 6291456
    float* gq   = ws + 6291456;          // 1048576
    float* gk   = ws + 7340032;          // 1048576
    float* Scf  = ws + 8388608;          // 4194304
    float* Zcf  = ws + 12582912;         // 32768
    float* ball = ws + 12615680;         // 3072
    float* b2a  = ws + 12618752;         // 1024
    _Float16* Xh  = (_Float16*)(ws + 12619776);   // 1048576 halves
    _Float16* WTa = Xh + 1048576;                 // 1572864
    _Float16* W2T = WTa + 1572864;                // 1048576
    _Float16* Y2h = W2T + 1048576;                // 2097152

    int out_mode = (out_size == 2048 * 1024) ? 1 : 0;

    xconv_kernel<<<1024, 256, 0, stream>>>(x, Xh);
    biasprep_kernel<<<16, 256, 0, stream>>>(q_br, q_bi, k_br, k_bi, v_br, v_bi,
                                            o_br, o_bi, ball, b2a);
    wconv_kernel<<<dim3(8, 8, 6), 256, 0, stream>>>(q_wr, q_wi, k_wr, k_wi, v_wr, v_wi, WTa);
    w2prep_kernel<<<dim3(16, 16), 256, 0, stream>>>(o_wr, o_wi, W2T);

    gemm_f16_kernel<<<dim3(24, 16), 256, 0, stream>>>(Xh, WTa, ball, Y1, 512, 3072, 0);

    feature_kernel<<<4096, 256, 0, stream>>>(Y1, gq, gk);

    chunkstate_kernel<<<512, 256, 0, stream>>>(Y1, gk, log_decay_s, log_decay_z, phase,
                                               (float2*)Scf, Zcf);

    chunkscan_kernel<<<dim3(8, 17), 256, 0, stream>>>(log_decay_s, log_decay_z, phase,
                                                      (float2*)Scf, Zcf);

    chunkout_kernel<<<512, 256, 0, stream>>>(Y1, gq, gk, (const float2*)Scf, Zcf,
                                             log_decay_s, log_decay_z, phase, Y2h);

    if (out_mode == 1) {
        gemm_f16_kernel<<<dim3(8, 16), 256, 0, stream>>>(Y2h, W2T, b2a, (float*)d_out,
                                                         1024, 1024, 1);
    } else {
        gemm_f16_kernel<<<dim3(4, 16), 256, 0, stream>>>(Y2h, W2T, b2a, (float*)d_out,
                                                         1024, 512, 0);
    }
}

// Round 5
// 79.929 us; speedup vs baseline: 17.5175x; 1.1541x over previous
//
#include <hip/hip_runtime.h>
#include <math.h>

#define TT 2048
#define NH 8
#define HDD 64
#define CL 32          // chunk length
#define NC 64          // number of chunks
#define EPS_F 1e-8f

typedef __attribute__((ext_vector_type(8))) _Float16 half8;
typedef __attribute__((ext_vector_type(4))) _Float16 half4;
typedef __attribute__((ext_vector_type(4))) float    f32x4;

__device__ __forceinline__ half8 neg8(half8 v) {
    half8 r;
    #pragma unroll
    for (int i = 0; i < 8; ++i) r[i] = -v[i];
    return r;
}
__device__ __forceinline__ unsigned int pack2h(float a, float b) {
    union { _Float16 h[2]; unsigned int u; } z;
    z.h[0] = (_Float16)a; z.h[1] = (_Float16)b; return z.u;
}
__device__ __forceinline__ float2 unpack2h(unsigned int w) {
    union { unsigned int u; _Float16 h[2]; } z; z.u = w;
    return make_float2((float)z.h[0], (float)z.h[1]);
}

// ---------------------------------------------------------------------------
// xconv: fp32 -> fp16
// ---------------------------------------------------------------------------
__global__ void xconv_kernel(const float* __restrict__ X, _Float16* __restrict__ Xh)
{
    int i4 = blockIdx.x * 256 + threadIdx.x;
    float4 v = ((const float4*)X)[i4];
    half4 o;
    o[0] = (_Float16)v.x; o[1] = (_Float16)v.y;
    o[2] = (_Float16)v.z; o[3] = (_Float16)v.w;
    ((half4*)Xh)[i4] = o;
}

// ---------------------------------------------------------------------------
// biasprep: GEMM1 bias packed in WT-row interleave; GEMM2 bias flat.
// WT row R = g*1024 + (n>>4)*32 + p*16 + (n&15)
// ---------------------------------------------------------------------------
__global__ void biasprep_kernel(
    const float* __restrict__ bq_r, const float* __restrict__ bq_i,
    const float* __restrict__ bk_r, const float* __restrict__ bk_i,
    const float* __restrict__ bv_r, const float* __restrict__ bv_i,
    const float* __restrict__ o_br, const float* __restrict__ o_bi,
    float* __restrict__ ball, float* __restrict__ b2a)
{
    int idx = blockIdx.x * 256 + threadIdx.x;   // 0..4095
    if (idx < 3072) {
        int g = idx >> 10, w = idx & 1023;
        int p = (w >> 4) & 1;
        int n = ((w >> 5) << 4) | (w & 15);
        float v;
        switch (g * 2 + p) {
          case 0: v = bq_r[n]; break;
          case 1: v = bq_i[n]; break;
          case 2: v = bk_r[n]; break;
          case 3: v = bk_i[n]; break;
          case 4: v = bv_r[n]; break;
          default: v = bv_i[n]; break;
        }
        ball[idx] = v;
    } else {
        int j = idx - 3072;
        b2a[j] = (j < 512) ? o_br[j] : o_bi[j - 512];
    }
}

// ---------------------------------------------------------------------------
// wconv: projection weights -> WT[3072][512] fp16, rows interleaved:
//   R = g*1024 + ((n>>4)<<5) + p*16 + (n&15),  WT[R][k] = Wg_p[k][n]
// grid (8 k-tiles, 8 n-tiles, 12 = g*2+p)
// ---------------------------------------------------------------------------
__global__ __launch_bounds__(256) void wconv_kernel(
    const float* __restrict__ Wq_r, const float* __restrict__ Wq_i,
    const float* __restrict__ Wk_r, const float* __restrict__ Wk_i,
    const float* __restrict__ Wv_r, const float* __restrict__ Wv_i,
    _Float16* __restrict__ WT)
{
    __shared__ float tile[64][65];
    const int tid = threadIdx.x;
    const int k0 = blockIdx.x * 64, n0 = blockIdx.y * 64, z = blockIdx.z;
    const int g = z >> 1, p = z & 1;
    const float* W;
    switch (z) {
      case 0: W = Wq_r; break;
      case 1: W = Wq_i; break;
      case 2: W = Wk_r; break;
      case 3: W = Wk_i; break;
      case 4: W = Wv_r; break;
      default: W = Wv_i; break;
    }
    #pragma unroll
    for (int it = 0; it < 16; ++it) {
        int idx = it * 256 + tid;
        tile[idx >> 6][idx & 63] = W[(size_t)(k0 + (idx >> 6)) * 512 + n0 + (idx & 63)];
    }
    __syncthreads();
    #pragma unroll
    for (int it = 0; it < 16; ++it) {
        int idx = it * 256 + tid;
        int nr = idx >> 6, kc = idx & 63;
        int n = n0 + nr;
        int R = g * 1024 + ((n >> 4) << 5) + p * 16 + (n & 15);
        WT[(size_t)R * 512 + k0 + kc] = (_Float16)tile[kc][nr];
    }
}

// ---------------------------------------------------------------------------
// w2prep: combined real output-projection weight, transposed + fp16
// ---------------------------------------------------------------------------
__global__ __launch_bounds__(256) void w2prep_kernel(
    const float* __restrict__ o_wr, const float* __restrict__ o_wi,
    _Float16* __restrict__ W2T)
{
    __shared__ float tile[64][65];
    const int tid = threadIdx.x;
    const int i0 = blockIdx.x * 64, j0 = blockIdx.y * 64;
    const float* src; float sgn; int io, jo;
    if (i0 < 512) {
        if (j0 < 512) { src = o_wr; sgn = 1.f;  io = i0; jo = j0; }
        else          { src = o_wi; sgn = 1.f;  io = i0; jo = j0 - 512; }
    } else {
        if (j0 < 512) { src = o_wi; sgn = -1.f; io = i0 - 512; jo = j0; }
        else          { src = o_wr; sgn = 1.f;  io = i0 - 512; jo = j0 - 512; }
    }
    #pragma unroll
    for (int it = 0; it < 16; ++it) {
        int idx = it * 256 + tid;
        tile[idx >> 6][idx & 63] = sgn * src[(size_t)(io + (idx >> 6)) * 512 + jo + (idx & 63)];
    }
    __syncthreads();
    #pragma unroll
    for (int it = 0; it < 16; ++it) {
        int idx = it * 256 + tid;
        int nr = idx >> 6, kc = idx & 63;
        W2T[(size_t)(j0 + nr) * 1024 + i0 + kc] = (_Float16)tile[kc][nr];
    }
}

// ---------------------------------------------------------------------------
// GEMM1 fused with feature epilogue. A = Xh[2048][512], B = WT (interleaved
// rows). Writes 8 fp16 planes: qfr,qfi,gq,kkr,kki,gk,vr,vi each [2048][512].
// grid (24 n-tiles, 16 m-tiles), 256 threads
// ---------------------------------------------------------------------------
__global__ __launch_bounds__(256) void gemm_qkv_kernel(
    const _Float16* __restrict__ A,
    const _Float16* __restrict__ BT,
    const float* __restrict__ ball,
    _Float16* __restrict__ PL)
{
    __shared__ _Float16 sA[128 * 32];
    __shared__ _Float16 sB[128 * 32];
    const int tid = threadIdx.x;
    const int bx = blockIdx.x, by = blockIdx.y;
    const int m0 = by * 128, R0 = bx * 128;
    const int g = bx >> 3;                 // 0=q,1=k,2=v
    const int nb = (bx & 7) * 64;          // logical col base
    const int lane = tid & 63;
    const int w = tid >> 6, wm = w >> 1, wn = w & 1;
    const int quad = lane >> 4, l15 = lane & 15;

    f32x4 acc[4][4];
    #pragma unroll
    for (int i = 0; i < 4; ++i)
        #pragma unroll
        for (int j = 0; j < 4; ++j) { f32x4 z = {0.f, 0.f, 0.f, 0.f}; acc[i][j] = z; }

    const int r0 = tid >> 2, r1 = (tid >> 2) + 64;
    const int sq = tid & 3;
    const _Float16* gA0 = A + (size_t)(m0 + r0) * 512 + (sq ^ ((r0 >> 1) & 3)) * 8;
    const _Float16* gA1 = A + (size_t)(m0 + r1) * 512 + (sq ^ ((r1 >> 1) & 3)) * 8;
    const _Float16* gB0 = BT + (size_t)(R0 + r0) * 512 + (sq ^ ((r0 >> 1) & 3)) * 8;
    const _Float16* gB1 = BT + (size_t)(R0 + r1) * 512 + (sq ^ ((r1 >> 1) & 3)) * 8;
    _Float16* wA0 = &sA[r0 * 32 + sq * 8];
    _Float16* wA1 = &sA[r1 * 32 + sq * 8];
    _Float16* wB0 = &sB[r0 * 32 + sq * 8];
    _Float16* wB1 = &sB[r1 * 32 + sq * 8];

    float4 pa0 = *(const float4*)gA0, pa1 = *(const float4*)gA1;
    float4 pb0 = *(const float4*)gB0, pb1 = *(const float4*)gB1;

    const int arow = wm * 64 + l15;
    const int brow = wn * 64 + l15;

    for (int ks = 0; ks < 16; ++ks) {
        *(float4*)wA0 = pa0; *(float4*)wA1 = pa1;
        *(float4*)wB0 = pb0; *(float4*)wB1 = pb1;
        __syncthreads();
        if (ks + 1 < 16) {
            int ko = (ks + 1) << 5;
            pa0 = *(const float4*)(gA0 + ko); pa1 = *(const float4*)(gA1 + ko);
            pb0 = *(const float4*)(gB0 + ko); pb1 = *(const float4*)(gB1 + ko);
        }
        half8 af[4], bf[4];
        #pragma unroll
        for (int mt = 0; mt < 4; ++mt) {
            int r = arow + mt * 16;
            int qp = quad ^ ((r >> 1) & 3);
            af[mt] = *(half8*)&sA[r * 32 + qp * 8];
        }
        #pragma unroll
        for (int nt = 0; nt < 4; ++nt) {
            int r = brow + nt * 16;
            int qp = quad ^ ((r >> 1) & 3);
            bf[nt] = *(half8*)&sB[r * 32 + qp * 8];
        }
        #pragma unroll
        for (int mt = 0; mt < 4; ++mt)
            #pragma unroll
            for (int nt = 0; nt < 4; ++nt)
                acc[mt][nt] = __builtin_amdgcn_mfma_f32_16x16x32_f16(af[mt], bf[nt], acc[mt][nt], 0, 0, 0);
        __syncthreads();
    }

    // plane pointers
    _Float16* qfr = PL;
    _Float16* qfi = PL + 1048576;
    _Float16* gqp = PL + 2097152;
    _Float16* kkr = PL + 3145728;
    _Float16* kki = PL + 4194304;
    _Float16* gkp = PL + 5242880;
    _Float16* vrp = PL + 6291456;
    _Float16* vip = PL + 7340032;

    const int crow0 = m0 + wm * 64 + quad * 4;
    #pragma unroll
    for (int j = 0; j < 2; ++j) {
        int col = nb + wn * 32 + j * 16 + l15;
        float bre = ball[R0 + wn * 64 + j * 32 + l15];
        float bim = ball[R0 + wn * 64 + j * 32 + 16 + l15];
        #pragma unroll
        for (int mt = 0; mt < 4; ++mt) {
            #pragma unroll
            for (int reg = 0; reg < 4; ++reg) {
                int row = crow0 + mt * 16 + reg;
                size_t ofs = (size_t)row * 512 + col;
                float xr = acc[mt][2 * j][reg] + bre;
                float xi = acc[mt][2 * j + 1][reg] + bim;
                if (g == 0) {
                    float gv = sqrtf(xr * xr + xi * xi);
                    float f = gv / (gv + EPS_F);
                    qfr[ofs] = (_Float16)(xr * f);
                    qfi[ofs] = (_Float16)(xi * f);
                    gqp[ofs] = (_Float16)gv;
                } else if (g == 1) {
                    float gv = sqrtf(xr * xr + xi * xi);
                    float f = gv / (gv + EPS_F);
                    kkr[ofs] = (_Float16)(xr * f);
                    kki[ofs] = (_Float16)(-xi * f);   // conj
                    gkp[ofs] = (_Float16)gv;
                } else {
                    vrp[ofs] = (_Float16)xr;
                    vip[ofs] = (_Float16)xi;
                }
            }
        }
    }
}

// ---------------------------------------------------------------------------
// GEMM2 (unchanged): out = Y2h @ W2T^T + b2a, complex interleave epilogue
// ---------------------------------------------------------------------------
__global__ __launch_bounds__(256) void gemm_f16_kernel(
    const _Float16* __restrict__ A,
    const _Float16* __restrict__ BT,
    const float* __restrict__ bias,
    float* __restrict__ C,
    int K, int ldc, int wmode)
{
    __shared__ _Float16 sA[128 * 32];
    __shared__ _Float16 sB[128 * 32];
    const int tid = threadIdx.x;
    const int m0 = blockIdx.y * 128, n0 = blockIdx.x * 128;
    const int lane = tid & 63;
    const int w = tid >> 6, wm = w >> 1, wn = w & 1;

    f32x4 acc[4][4];
    #pragma unroll
    for (int i = 0; i < 4; ++i)
        #pragma unroll
        for (int j = 0; j < 4; ++j) { f32x4 z = {0.f, 0.f, 0.f, 0.f}; acc[i][j] = z; }

    const int r0 = tid >> 2, r1 = (tid >> 2) + 64;
    const int sq = tid & 3;
    const _Float16* gA0 = A + (size_t)(m0 + r0) * K + (sq ^ ((r0 >> 1) & 3)) * 8;
    const _Float16* gA1 = A + (size_t)(m0 + r1) * K + (sq ^ ((r1 >> 1) & 3)) * 8;
    const _Float16* gB0 = BT + (size_t)(n0 + r0) * K + (sq ^ ((r0 >> 1) & 3)) * 8;
    const _Float16* gB1 = BT + (size_t)(n0 + r1) * K + (sq ^ ((r1 >> 1) & 3)) * 8;
    _Float16* wA0 = &sA[r0 * 32 + sq * 8];
    _Float16* wA1 = &sA[r1 * 32 + sq * 8];
    _Float16* wB0 = &sB[r0 * 32 + sq * 8];
    _Float16* wB1 = &sB[r1 * 32 + sq * 8];

    float4 pa0 = *(const float4*)gA0, pa1 = *(const float4*)gA1;
    float4 pb0 = *(const float4*)gB0, pb1 = *(const float4*)gB1;

    const int arow = wm * 64 + (lane & 15);
    const int brow = wn * 64 + (lane & 15);
    const int nsteps = K >> 5;

    for (int ks = 0; ks < nsteps; ++ks) {
        *(float4*)wA0 = pa0; *(float4*)wA1 = pa1;
        *(float4*)wB0 = pb0; *(float4*)wB1 = pb1;
        __syncthreads();
        if (ks + 1 < nsteps) {
            int ko = (ks + 1) << 5;
            pa0 = *(const float4*)(gA0 + ko); pa1 = *(const float4*)(gA1 + ko);
            pb0 = *(const float4*)(gB0 + ko); pb1 = *(const float4*)(gB1 + ko);
        }
        half8 af[4], bf[4];
        #pragma unroll
        for (int mt = 0; mt < 4; ++mt) {
            int r = arow + mt * 16;
            int qp = (lane >> 4) ^ ((r >> 1) & 3);
            af[mt] = *(half8*)&sA[r * 32 + qp * 8];
        }
        #pragma unroll
        for (int nt = 0; nt < 4; ++nt) {
            int r = brow + nt * 16;
            int qp = (lane >> 4) ^ ((r >> 1) & 3);
            bf[nt] = *(half8*)&sB[r * 32 + qp * 8];
        }
        #pragma unroll
        for (int mt = 0; mt < 4; ++mt)
            #pragma unroll
            for (int nt = 0; nt < 4; ++nt)
                acc[mt][nt] = __builtin_amdgcn_mfma_f32_16x16x32_f16(af[mt], bf[nt], acc[mt][nt], 0, 0, 0);
        __syncthreads();
    }

    const int crow0 = m0 + wm * 64 + (lane >> 4) * 4;
    const int ccol0 = n0 + wn * 64 + (lane & 15);
    #pragma unroll
    for (int mt = 0; mt < 4; ++mt) {
        #pragma unroll
        for (int nt = 0; nt < 4; ++nt) {
            int col = ccol0 + nt * 16;
            float b = bias[col];
            #pragma unroll
            for (int rg = 0; rg < 4; ++rg) {
                int row = crow0 + mt * 16 + rg;
                float val = acc[mt][nt][rg] + b;
                if (wmode == 0) {
                    C[(size_t)row * ldc + col] = val;
                } else {
                    int off = (col < 512) ? (row * 1024 + 2 * col) : (row * 1024 + 2 * (col - 512) + 1);
                    C[off] = val;
                }
            }
        }
    }
}

// ---------------------------------------------------------------------------
// chunkstate: MFMA, reads fp16 planes, writes Sc as packed half2 (uint)
// ---------------------------------------------------------------------------
__global__ __launch_bounds__(256) void chunkstate_kernel(
    const _Float16* __restrict__ PL,
    const float* __restrict__ lgs, const float* __restrict__ lgz,
    const float* __restrict__ phs,
    unsigned int* __restrict__ ScU, float* __restrict__ Zc)
{
    __shared__ _Float16 wvTr[64 * 40], wvTi[64 * 40];                  // [vd][u]
    __shared__ _Float16 kkTr[64 * 40], kkTi[64 * 40], kkTiN[64 * 40];  // [k][u]
    __shared__ float    Lgkz[32 * 65];                                 // [u][k]

    const int tid = threadIdx.x;
    const int c = blockIdx.x & 63, h = blockIdx.x >> 6;

    float xs = lgs[h];
    float sps = fmaxf(xs, 0.f) + log1pf(expf(-fabsf(xs)));
    float ph = phs[h];
    float xz = lgz[h];
    float spz = fmaxf(xz, 0.f) + log1pf(expf(-fabsf(xz)));

    const _Float16* kkrP = PL + 3145728;
    const _Float16* kkiP = PL + 4194304;
    const _Float16* gkpP = PL + 5242880;
    const _Float16* vrP  = PL + 6291456;
    const _Float16* viP  = PL + 7340032;

    {
        const int u = tid >> 3, ks = (tid & 7) << 3;
        const size_t rofs = (size_t)(c * CL + u) * 512 + h * HDD + ks;
        half8 kr8 = *(const half8*)&kkrP[rofs];
        half8 ki8 = *(const half8*)&kkiP[rofs];
        half8 gk8 = *(const half8*)&gkpP[rofs];
        half8 vr8 = *(const half8*)&vrP[rofs];
        half8 vi8 = *(const half8*)&viP[rofs];
        float e = (float)(CL - 1 - u);
        float r = expf(-sps * e);
        float wAr = r * cosf(ph * e), wAi = r * sinf(ph * e);
        float wz = expf(-spz * e);
        #pragma unroll
        for (int j = 0; j < 8; ++j) {
            int kcol = ks + j;
            kkTr[kcol * 40 + u]  = kr8[j];
            kkTi[kcol * 40 + u]  = ki8[j];
            kkTiN[kcol * 40 + u] = -ki8[j];
            float vre = (float)vr8[j], vim = (float)vi8[j];
            wvTr[kcol * 40 + u] = (_Float16)(wAr * vre - wAi * vim);
            wvTi[kcol * 40 + u] = (_Float16)(wAr * vim + wAi * vre);
            Lgkz[u * 65 + kcol] = wz * (float)gk8[j];
        }
    }
    __syncthreads();

    const int w = tid >> 6, lane = tid & 63;
    const int quad = lane >> 4, l15 = lane & 15;
    const int arow = (w * 16 + l15) * 40 + quad * 8;
    half8 fvr = *(const half8*)&wvTr[arow];
    half8 fvi = *(const half8*)&wvTi[arow];
    unsigned int* out = ScU + ((size_t)(c * NH + h) << 12);
    #pragma unroll
    for (int kq = 0; kq < 4; ++kq) {
        int brow = (kq * 16 + l15) * 40 + quad * 8;
        half8 fkr  = *(const half8*)&kkTr[brow];
        half8 fki  = *(const half8*)&kkTi[brow];
        half8 fkiN = *(const half8*)&kkTiN[brow];
        f32x4 Cr = {0.f, 0.f, 0.f, 0.f}, Ci = {0.f, 0.f, 0.f, 0.f};
        Cr = __builtin_amdgcn_mfma_f32_16x16x32_f16(fvr, fkr,  Cr, 0, 0, 0);
        Cr = __builtin_amdgcn_mfma_f32_16x16x32_f16(fvi, fkiN, Cr, 0, 0, 0);
        Ci = __builtin_amdgcn_mfma_f32_16x16x32_f16(fvr, fki,  Ci, 0, 0, 0);
        Ci = __builtin_amdgcn_mfma_f32_16x16x32_f16(fvi, fkr,  Ci, 0, 0, 0);
        #pragma unroll
        for (int reg = 0; reg < 4; ++reg) {
            int vd = w * 16 + quad * 4 + reg;
            out[vd * 64 + kq * 16 + l15] = pack2h(Cr[reg], Ci[reg]);
        }
    }
    if (tid < 64) {
        float z = 0.f;
        #pragma unroll
        for (int uu = 0; uu < 32; ++uu) z += Lgkz[uu * 65 + tid];
        Zc[(c * NH + h) * 64 + tid] = z;
    }
}

// ---------------------------------------------------------------------------
// chunkscan: exclusive prefix over chunks, fp16 packed state, pipelined loads.
// grid 130 blocks: 0..127 -> S elements (packed half2); 128..129 -> Z (fp32)
// ---------------------------------------------------------------------------
__global__ __launch_bounds__(256) void chunkscan_kernel(
    const float* __restrict__ lgs, const float* __restrict__ lgz,
    const float* __restrict__ phs,
    unsigned int* __restrict__ ScU, float* __restrict__ Zc)
{
    const int bid = blockIdx.x, tid = threadIdx.x;
    if (bid < 128) {
        const int idx = bid * 256 + tid;
        const int h = idx >> 12, e = idx & 4095;
        float xs = lgs[h];
        float sps = fmaxf(xs, 0.f) + log1pf(expf(-fabsf(xs)));
        float ph = phs[h];
        float r = expf(-sps * (float)CL);
        float aLr = r * cosf(ph * (float)CL), aLi = r * sinf(ph * (float)CL);
        unsigned int* p = ScU + (size_t)h * 4096 + e;
        float pr = 0.f, pi = 0.f;
        #pragma unroll
        for (int cb = 0; cb < 8; ++cb) {
            unsigned int v[8];
            #pragma unroll
            for (int j = 0; j < 8; ++j) v[j] = p[(size_t)((cb << 3) + j) * 32768];
            #pragma unroll
            for (int j = 0; j < 8; ++j) {
                float2 tmp = unpack2h(v[j]);
                p[(size_t)((cb << 3) + j) * 32768] = pack2h(pr, pi);
                float nr = aLr * pr - aLi * pi + tmp.x;
                float ni = aLr * pi + aLi * pr + tmp.y;
                pr = nr; pi = ni;
            }
        }
    } else {
        const int idx = (bid - 128) * 256 + tid;
        const int h = idx >> 6, k = idx & 63;
        float xz = lgz[h];
        float spz = fmaxf(xz, 0.f) + log1pf(expf(-fabsf(xz)));
        float azL = expf(-spz * (float)CL);
        float* p = Zc + h * 64 + k;
        float prev = 0.f;
        #pragma unroll
        for (int cb = 0; cb < 8; ++cb) {
            float v[8];
            #pragma unroll
            for (int j = 0; j < 8; ++j) v[j] = p[(size_t)((cb << 3) + j) * 512];
            #pragma unroll
            for (int j = 0; j < 8; ++j) {
                float tmp = v[j];
                p[(size_t)((cb << 3) + j) * 512] = prev;
                prev = azL * prev + tmp;
            }
        }
    }
}

// ---------------------------------------------------------------------------
// chunkout: MFMA, reads fp16 planes + packed Sp; writes Y2h fp16.
// ---------------------------------------------------------------------------
__global__ __launch_bounds__(256) void chunkout_kernel(
    const _Float16* __restrict__ PL,
    const unsigned int* __restrict__ SpU, const float* __restrict__ Zp,
    const float* __restrict__ lgs, const float* __restrict__ lgz,
    const float* __restrict__ phs,
    _Float16* __restrict__ Y2h)
{
    __shared__ _Float16 Lqr[32 * 72], Lqi[32 * 72], LqiN[32 * 72];   // [t][k]
    __shared__ _Float16 Lkr[32 * 72], Lki[32 * 72], LkiN[32 * 72];   // [u][k]
    __shared__ _Float16 Lgq[32 * 72], Lgk[32 * 72];
    __shared__ _Float16 Spr[64 * 72], Spi[64 * 72];                  // [vd][k]
    __shared__ _Float16 Vtr[64 * 40], Vti[64 * 40];                  // [vd][u]
    __shared__ _Float16 Wr_[32 * 32], Wi_[32 * 32], WiN[32 * 32];    // [t][u]
    __shared__ float  sDenP[2][32], sZdot[32], sDinv[32], sZp[64];
    __shared__ float2 s_apow[CL + 1];
    __shared__ float  s_azpow[CL + 1];

    const int tid = threadIdx.x;
    const int c = blockIdx.x & 63, h = blockIdx.x >> 6;

    if (tid <= CL) {
        float xs = lgs[h];
        float sps = fmaxf(xs, 0.f) + log1pf(expf(-fabsf(xs)));
        float ph = phs[h];
        float r = expf(-sps * (float)tid);
        s_apow[tid] = make_float2(r * cosf(ph * (float)tid), r * sinf(ph * (float)tid));
        float xz = lgz[h];
        float spz = fmaxf(xz, 0.f) + log1pf(expf(-fabsf(xz)));
        s_azpow[tid] = expf(-spz * (float)tid);
    }
    if (tid < 64) sZp[tid] = Zp[(c * NH + h) * 64 + tid];

    const _Float16* qfrP = PL;
    const _Float16* qfiP = PL + 1048576;
    const _Float16* gqpP = PL + 2097152;
    const _Float16* kkrP = PL + 3145728;
    const _Float16* kkiP = PL + 4194304;
    const _Float16* gkpP = PL + 5242880;
    const _Float16* vrP  = PL + 6291456;
    const _Float16* viP  = PL + 7340032;

    // ---- staging: planes -> LDS ----
    {
        const int u = tid >> 3, ks = (tid & 7) << 3;
        const size_t rofs = (size_t)(c * CL + u) * 512 + h * HDD + ks;
        half8 qr  = *(const half8*)&qfrP[rofs];
        half8 qi  = *(const half8*)&qfiP[rofs];
        half8 g8q = *(const half8*)&gqpP[rofs];
        half8 kr  = *(const half8*)&kkrP[rofs];
        half8 ki  = *(const half8*)&kkiP[rofs];
        half8 g8k = *(const half8*)&gkpP[rofs];
        half8 vr8 = *(const half8*)&vrP[rofs];
        half8 vi8 = *(const half8*)&viP[rofs];
        int ofs = u * 72 + ks;
        *(half8*)&Lqr[ofs] = qr;  *(half8*)&Lqi[ofs] = qi;  *(half8*)&LqiN[ofs] = neg8(qi);
        *(half8*)&Lkr[ofs] = kr;  *(half8*)&Lki[ofs] = ki;  *(half8*)&LkiN[ofs] = neg8(ki);
        *(half8*)&Lgq[ofs] = g8q; *(half8*)&Lgk[ofs] = g8k;
        #pragma unroll
        for (int j = 0; j < 8; ++j) {
            Vtr[(ks + j) * 40 + u] = vr8[j];
            Vti[(ks + j) * 40 + u] = vi8[j];
        }
    }
    // ---- staging: packed Sp -> fp16 planes ----
    {
        const int vd = tid >> 2, k0 = (tid & 3) << 4;
        const unsigned int* gp = SpU + ((size_t)(c * NH + h) << 12) + vd * 64 + k0;
        half8 p0r, p0i, p1r, p1i;
        #pragma unroll
        for (int j = 0; j < 8; ++j) {
            union { unsigned int u; _Float16 hh[2]; } z0, z1;
            z0.u = gp[j]; z1.u = gp[8 + j];
            p0r[j] = z0.hh[0]; p0i[j] = z0.hh[1];
            p1r[j] = z1.hh[0]; p1i[j] = z1.hh[1];
        }
        int ofs = vd * 72 + k0;
        *(half8*)&Spr[ofs]     = p0r; *(half8*)&Spr[ofs + 8] = p1r;
        *(half8*)&Spi[ofs]     = p0i; *(half8*)&Spi[ofs + 8] = p1i;
    }
    __syncthreads();

    // ---- zdot[t] = Zp . gq[t] ----
    {
        const int t = tid >> 3, k8 = (tid & 7) << 3;
        float z = 0.f;
        #pragma unroll
        for (int j = 0; j < 8; ++j) z += sZp[k8 + j] * (float)Lgq[t * 72 + k8 + j];
        z += __shfl_xor(z, 1); z += __shfl_xor(z, 2); z += __shfl_xor(z, 4);
        if ((tid & 7) == 0) sZdot[t] = z;
    }

    const int w = tid >> 6, lane = tid & 63;
    const int quad = lane >> 4, l15 = lane & 15;
    const int th = w >> 1, uh = w & 1;
    const f32x4 zero = {0.f, 0.f, 0.f, 0.f};

    // ---- phase 1a: scores + den ----
    f32x4 Ar = zero, Ai = zero, Dn = zero;
    {
        const int qrow = (th * 16 + l15) * 72;
        const int krow = (uh * 16 + l15) * 72;
        #pragma unroll
        for (int s = 0; s < 2; ++s) {
            int ko = s * 32 + quad * 8;
            half8 fqr  = *(const half8*)&Lqr[qrow + ko];
            half8 fqi  = *(const half8*)&Lqi[qrow + ko];
            half8 fkr  = *(const half8*)&Lkr[krow + ko];
            half8 fki  = *(const half8*)&Lki[krow + ko];
            half8 fkiN = *(const half8*)&LkiN[krow + ko];
            Ar = __builtin_amdgcn_mfma_f32_16x16x32_f16(fqr, fkr,  Ar, 0, 0, 0);
            Ar = __builtin_amdgcn_mfma_f32_16x16x32_f16(fqi, fkiN, Ar, 0, 0, 0);
            Ai = __builtin_amdgcn_mfma_f32_16x16x32_f16(fqr, fki,  Ai, 0, 0, 0);
            Ai = __builtin_amdgcn_mfma_f32_16x16x32_f16(fqi, fkr,  Ai, 0, 0, 0);
            half8 fgq = *(const half8*)&Lgq[qrow + ko];
            half8 fgk = *(const half8*)&Lgk[krow + ko];
            Dn = __builtin_amdgcn_mfma_f32_16x16x32_f16(fgq, fgk, Dn, 0, 0, 0);
        }
    }
    // ---- phase 1b: inter = Sp @ qf ----
    f32x4 IRr[2] = {zero, zero}, IRi[2] = {zero, zero};
    {
        const int prow = (w * 16 + l15) * 72;
        #pragma unroll
        for (int s = 0; s < 2; ++s) {
            int ko = s * 32 + quad * 8;
            half8 fSr = *(const half8*)&Spr[prow + ko];
            half8 fSi = *(const half8*)&Spi[prow + ko];
            #pragma unroll
            for (int t2 = 0; t2 < 2; ++t2) {
                int qrow = (t2 * 16 + l15) * 72 + ko;
                half8 fqr  = *(const half8*)&Lqr[qrow];
                half8 fqi  = *(const half8*)&Lqi[qrow];
                half8 fqiN = *(const half8*)&LqiN[qrow];
                IRr[t2] = __builtin_amdgcn_mfma_f32_16x16x32_f16(fSr, fqr,  IRr[t2], 0, 0, 0);
                IRr[t2] = __builtin_amdgcn_mfma_f32_16x16x32_f16(fSi, fqiN, IRr[t2], 0, 0, 0);
                IRi[t2] = __builtin_amdgcn_mfma_f32_16x16x32_f16(fSr, fqi,  IRi[t2], 0, 0, 0);
                IRi[t2] = __builtin_amdgcn_mfma_f32_16x16x32_f16(fSi, fqr,  IRi[t2], 0, 0, 0);
            }
        }
    }
    // ---- mask + decay -> sW; den partials ----
    #pragma unroll
    for (int reg = 0; reg < 4; ++reg) {
        int t = th * 16 + quad * 4 + reg;
        int u = uh * 16 + l15;
        float wr = 0.f, wi = 0.f, dd = 0.f;
        if (u <= t) {
            float2 p = s_apow[t - u];
            wr = p.x * Ar[reg] - p.y * Ai[reg];
            wi = p.x * Ai[reg] + p.y * Ar[reg];
            dd = s_azpow[t - u] * Dn[reg];
        }
        Wr_[t * 32 + u] = (_Float16)wr;
        Wi_[t * 32 + u] = (_Float16)wi;
        WiN[t * 32 + u] = (_Float16)(-wi);
        dd += __shfl_xor(dd, 1); dd += __shfl_xor(dd, 2);
        dd += __shfl_xor(dd, 4); dd += __shfl_xor(dd, 8);
        if (l15 == 0) sDenP[uh][t] = dd;
    }
    __syncthreads();

    if (tid < 32) {
        float den = sDenP[0][tid] + sDenP[1][tid] + s_azpow[tid + 1] * sZdot[tid];
        sDinv[tid] = 1.f / (den + EPS_F);
    }

    // ---- phase 2: intra = vT @ sW^T ----
    f32x4 NRr[2] = {zero, zero}, NRi[2] = {zero, zero};
    {
        const int vrow = (w * 16 + l15) * 40 + quad * 8;
        half8 fvr = *(const half8*)&Vtr[vrow];
        half8 fvi = *(const half8*)&Vti[vrow];
        #pragma unroll
        for (int t2 = 0; t2 < 2; ++t2) {
            int trow = (t2 * 16 + l15) * 32 + quad * 8;
            half8 fWr  = *(const half8*)&Wr_[trow];
            half8 fWi  = *(const half8*)&Wi_[trow];
            half8 fWiN = *(const half8*)&WiN[trow];
            NRr[t2] = __builtin_amdgcn_mfma_f32_16x16x32_f16(fvr, fWr,  NRr[t2], 0, 0, 0);
            NRr[t2] = __builtin_amdgcn_mfma_f32_16x16x32_f16(fvi, fWiN, NRr[t2], 0, 0, 0);
            NRi[t2] = __builtin_amdgcn_mfma_f32_16x16x32_f16(fvr, fWi,  NRi[t2], 0, 0, 0);
            NRi[t2] = __builtin_amdgcn_mfma_f32_16x16x32_f16(fvi, fWr,  NRi[t2], 0, 0, 0);
        }
    }
    __syncthreads();

    // ---- epilogue ----
    #pragma unroll
    for (int t2 = 0; t2 < 2; ++t2) {
        int t = t2 * 16 + l15;
        float2 fac = s_apow[t + 1];
        float dinv = sDinv[t];
        half4 hre, him;
        #pragma unroll
        for (int reg = 0; reg < 4; ++reg) {
            float rx = NRr[t2][reg] + fac.x * IRr[t2][reg] - fac.y * IRi[t2][reg];
            float ry = NRi[t2][reg] + fac.x * IRi[t2][reg] + fac.y * IRr[t2][reg];
            hre[reg] = (_Float16)(rx * dinv);
            him[reg] = (_Float16)(ry * dinv);
        }
        int vd0 = w * 16 + quad * 4;
        _Float16* orow = Y2h + (size_t)(c * CL + t) * 1024 + h * HDD;
        *(half4*)&orow[vd0]       = hre;
        *(half4*)&orow[512 + vd0] = him;
    }
}

// ---------------------------------------------------------------------------
extern "C" void kernel_launch(void* const* d_in, const int* in_sizes, int n_in,
                              void* d_out, int out_size, void* d_ws, size_t ws_size,
                              hipStream_t stream)
{
    const float* x    = (const float*)d_in[0];
    const float* q_wr = (const float*)d_in[1];
    const float* q_wi = (const float*)d_in[2];
    const float* q_br = (const float*)d_in[3];
    const float* q_bi = (const float*)d_in[4];
    const float* k_wr = (const float*)d_in[5];
    const float* k_wi = (const float*)d_in[6];
    const float* k_br = (const float*)d_in[7];
    const float* k_bi = (const float*)d_in[8];
    const float* v_wr = (const float*)d_in[9];
    const float* v_wi = (const float*)d_in[10];
    const float* v_br = (const float*)d_in[11];
    const float* v_bi = (const float*)d_in[12];
    const float* o_wr = (const float*)d_in[13];
    const float* o_wi = (const float*)d_in[14];
    const float* o_br = (const float*)d_in[15];
    const float* o_bi = (const float*)d_in[16];
    const float* log_decay_s = (const float*)d_in[17];
    const float* log_decay_z = (const float*)d_in[18];
    const float* phase       = (const float*)d_in[19];

    float* ws = (float*)d_ws;
    float* Zcf  = ws;                          // 32768
    float* ball = ws + 32768;                  // 3072
    float* b2a  = ws + 35840;                  // 1024
    _Float16* Xh  = (_Float16*)(ws + 36864);   // 1048576 h
    _Float16* WTa = Xh + 1048576;              // 1572864 h
    _Float16* W2T = WTa + 1572864;             // 1048576 h
    _Float16* Y2h = W2T + 1048576;             // 2097152 h
    _Float16* PL  = Y2h + 2097152;             // 8 planes x 1048576 h
    unsigned int* ScU = (unsigned int*)(PL + 8388608);  // 2097152 uints

    int out_mode = (out_size == 2048 * 1024) ? 1 : 0;

    xconv_kernel<<<1024, 256, 0, stream>>>(x, Xh);
    biasprep_kernel<<<16, 256, 0, stream>>>(q_br, q_bi, k_br, k_bi, v_br, v_bi,
                                            o_br, o_bi, ball, b2a);
    wconv_kernel<<<dim3(8, 8, 12), 256, 0, stream>>>(q_wr, q_wi, k_wr, k_wi, v_wr, v_wi, WTa);
    w2prep_kernel<<<dim3(16, 16), 256, 0, stream>>>(o_wr, o_wi, W2T);

    gemm_qkv_kernel<<<dim3(24, 16), 256, 0, stream>>>(Xh, WTa, ball, PL);

    chunkstate_kernel<<<512, 256, 0, stream>>>(PL, log_decay_s, log_decay_z, phase,
                                               ScU, Zcf);

    chunkscan_kernel<<<130, 256, 0, stream>>>(log_decay_s, log_decay_z, phase, ScU, Zcf);

    chunkout_kernel<<<512, 256, 0, stream>>>(PL, ScU, Zcf, log_decay_s, log_decay_z,
                                             phase, Y2h);

    if (out_mode == 1) {
        gemm_f16_kernel<<<dim3(8, 16), 256, 0, stream>>>(Y2h, W2T, b2a, (float*)d_out,
                                                         1024, 1024, 1);
    } else {
        gemm_f16_kernel<<<dim3(4, 16), 256, 0, stream>>>(Y2h, W2T, b2a, (float*)d_out,
                                                         1024, 512, 0);
    }
}

// Round 8
// 71.422 us; speedup vs baseline: 19.6040x; 1.1191x over previous
//
#include <hip/hip_runtime.h>
#include <math.h>

#define TT 2048
#define NH 8
#define HDD 64
#define CL 32          // chunk length
#define NC 64          // number of chunks
#define EPS_F 1e-8f

typedef __attribute__((ext_vector_type(8))) _Float16 half8;
typedef __attribute__((ext_vector_type(4))) _Float16 half4;
typedef __attribute__((ext_vector_type(4))) float    f32x4;

__device__ __forceinline__ unsigned int pack2h(float a, float b) {
    union { _Float16 h[2]; unsigned int u; } z;
    z.h[0] = (_Float16)a; z.h[1] = (_Float16)b; return z.u;
}
__device__ __forceinline__ float2 unpack2h(unsigned int w) {
    union { unsigned int u; _Float16 h[2]; } z; z.u = w;
    return make_float2((float)z.h[0], (float)z.h[1]);
}
// register-level negate: XOR fp16 sign bits
__device__ __forceinline__ half8 neg8r(half8 v) {
    union { half8 h; unsigned int u[4]; } z; z.h = v;
    #pragma unroll
    for (int i = 0; i < 4; ++i) z.u[i] ^= 0x80008000u;
    return z.h;
}
__device__ __forceinline__ half8 cvt8f(float4 a, float4 b) {
    half8 r;
    r[0]=(_Float16)a.x; r[1]=(_Float16)a.y; r[2]=(_Float16)a.z; r[3]=(_Float16)a.w;
    r[4]=(_Float16)b.x; r[5]=(_Float16)b.y; r[6]=(_Float16)b.z; r[7]=(_Float16)b.w;
    return r;
}

// ---------------------------------------------------------------------------
// prep: fused wconv (blocks 0..383, z = bid>>6 in 0..5) + w2prep (384..639)
//       + biasprep (640..655).  FIX: was 768 wconv blocks (z up to 11) whose
//       z>=6 blocks wrote OOB past WTa into W2T -> race with fused w2prep.
// ---------------------------------------------------------------------------
__global__ __launch_bounds__(256) void prep_kernel(
    const float* __restrict__ q_wr, const float* __restrict__ q_wi,
    const float* __restrict__ k_wr, const float* __restrict__ k_wi,
    const float* __restrict__ v_wr, const float* __restrict__ v_wi,
    const float* __restrict__ o_wr, const float* __restrict__ o_wi,
    const float* __restrict__ bq_r, const float* __restrict__ bq_i,
    const float* __restrict__ bk_r, const float* __restrict__ bk_i,
    const float* __restrict__ bv_r, const float* __restrict__ bv_i,
    const float* __restrict__ o_br, const float* __restrict__ o_bi,
    _Float16* __restrict__ WT, _Float16* __restrict__ W2T,
    float* __restrict__ ball, float* __restrict__ b2a)
{
    __shared__ float tile[64][65];
    const int bid = blockIdx.x, tid = threadIdx.x;
    if (bid < 384) {
        // wconv: WT[R][k] = Wg_p[k][n], R = g*1024 + ((n>>4)<<5) + p*16 + (n&15)
        const int z = bid >> 6, t = bid & 63;       // z in 0..5
        const int k0 = (t >> 3) * 64, n0 = (t & 7) * 64;
        const int g = z >> 1, p = z & 1;
        const float* W;
        switch (z) {
          case 0: W = q_wr; break;
          case 1: W = q_wi; break;
          case 2: W = k_wr; break;
          case 3: W = k_wi; break;
          case 4: W = v_wr; break;
          default: W = v_wi; break;                 // z == 5
        }
        #pragma unroll
        for (int it = 0; it < 16; ++it) {
            int idx = it * 256 + tid;
            tile[idx >> 6][idx & 63] = W[(size_t)(k0 + (idx >> 6)) * 512 + n0 + (idx & 63)];
        }
        __syncthreads();
        #pragma unroll
        for (int it = 0; it < 16; ++it) {
            int idx = it * 256 + tid;
            int nr = idx >> 6, kc = idx & 63;
            int n = n0 + nr;
            int R = g * 1024 + ((n >> 4) << 5) + p * 16 + (n & 15);
            WT[(size_t)R * 512 + k0 + kc] = (_Float16)tile[kc][nr];
        }
    } else if (bid < 640) {
        const int t = bid - 384;
        const int i0 = (t >> 4) * 64, j0 = (t & 15) * 64;
        const float* src; float sgn; int io, jo;
        if (i0 < 512) {
            if (j0 < 512) { src = o_wr; sgn = 1.f;  io = i0; jo = j0; }
            else          { src = o_wi; sgn = 1.f;  io = i0; jo = j0 - 512; }
        } else {
            if (j0 < 512) { src = o_wi; sgn = -1.f; io = i0 - 512; jo = j0; }
            else          { src = o_wr; sgn = 1.f;  io = i0 - 512; jo = j0 - 512; }
        }
        #pragma unroll
        for (int it = 0; it < 16; ++it) {
            int idx = it * 256 + tid;
            tile[idx >> 6][idx & 63] = sgn * src[(size_t)(io + (idx >> 6)) * 512 + jo + (idx & 63)];
        }
        __syncthreads();
        #pragma unroll
        for (int it = 0; it < 16; ++it) {
            int idx = it * 256 + tid;
            int nr = idx >> 6, kc = idx & 63;
            W2T[(size_t)(j0 + nr) * 1024 + i0 + kc] = (_Float16)tile[kc][nr];
        }
    } else {
        int idx = (bid - 640) * 256 + tid;   // 0..4095
        if (idx < 3072) {
            int g = idx >> 10, wq = idx & 1023;
            int p = (wq >> 4) & 1;
            int n = ((wq >> 5) << 4) | (wq & 15);
            float v;
            switch (g * 2 + p) {
              case 0: v = bq_r[n]; break;
              case 1: v = bq_i[n]; break;
              case 2: v = bk_r[n]; break;
              case 3: v = bk_i[n]; break;
              case 4: v = bv_r[n]; break;
              default: v = bv_i[n]; break;
            }
            ball[idx] = v;
        } else {
            int j = idx - 3072;
            b2a[j] = (j < 512) ? o_br[j] : o_bi[j - 512];
        }
    }
}

// ---------------------------------------------------------------------------
// GEMM1 fused w/ feature epilogue. A = X fp32 (converted during staging),
// B = WT fp16, both reg-staged (round-5-proven path).
// Writes 8 fp16 planes qfr,qfi,gq,kkr,kki,gk,vr,vi each [2048][512].
// ---------------------------------------------------------------------------
__global__ __launch_bounds__(256) void gemm_qkv_kernel(
    const float* __restrict__ X,
    const _Float16* __restrict__ BT,
    const float* __restrict__ ball,
    _Float16* __restrict__ PL)
{
    __shared__ _Float16 sA[128 * 32];
    __shared__ _Float16 sB[128 * 32];
    const int tid = threadIdx.x;
    const int bx = blockIdx.x, by = blockIdx.y;
    const int m0 = by * 128, R0 = bx * 128;
    const int g = bx >> 3;
    const int nb = (bx & 7) * 64;
    const int lane = tid & 63;
    const int w = tid >> 6, wm = w >> 1, wn = w & 1;
    const int quad = lane >> 4, l15 = lane & 15;

    f32x4 acc[4][4];
    #pragma unroll
    for (int i = 0; i < 4; ++i)
        #pragma unroll
        for (int j = 0; j < 4; ++j) { f32x4 z = {0.f, 0.f, 0.f, 0.f}; acc[i][j] = z; }

    const int r0 = tid >> 2, r1 = r0 + 64;
    const int sq = tid & 3;
    const float* gA0 = X + (size_t)(m0 + r0) * 512 + (sq ^ ((r0 >> 1) & 3)) * 8;
    const float* gA1 = X + (size_t)(m0 + r1) * 512 + (sq ^ ((r1 >> 1) & 3)) * 8;
    const _Float16* gB0 = BT + (size_t)(R0 + r0) * 512 + (sq ^ ((r0 >> 1) & 3)) * 8;
    const _Float16* gB1 = BT + (size_t)(R0 + r1) * 512 + (sq ^ ((r1 >> 1) & 3)) * 8;
    _Float16* wA0 = &sA[r0 * 32 + sq * 8];
    _Float16* wA1 = &sA[r1 * 32 + sq * 8];
    _Float16* wB0 = &sB[r0 * 32 + sq * 8];
    _Float16* wB1 = &sB[r1 * 32 + sq * 8];

    float4 a00 = *(const float4*)gA0, a01 = *(const float4*)(gA0 + 4);
    float4 a10 = *(const float4*)gA1, a11 = *(const float4*)(gA1 + 4);
    float4 pb0 = *(const float4*)gB0, pb1 = *(const float4*)gB1;

    const int arow = wm * 64 + l15;
    const int brow = wn * 64 + l15;

    for (int ks = 0; ks < 16; ++ks) {
        *(half8*)wA0 = cvt8f(a00, a01);
        *(half8*)wA1 = cvt8f(a10, a11);
        *(float4*)wB0 = pb0;
        *(float4*)wB1 = pb1;
        __syncthreads();
        if (ks + 1 < 16) {
            int ko = (ks + 1) << 5;
            a00 = *(const float4*)(gA0 + ko); a01 = *(const float4*)(gA0 + ko + 4);
            a10 = *(const float4*)(gA1 + ko); a11 = *(const float4*)(gA1 + ko + 4);
            pb0 = *(const float4*)(gB0 + ko); pb1 = *(const float4*)(gB1 + ko);
        }
        half8 af[4], bf[4];
        #pragma unroll
        for (int mt = 0; mt < 4; ++mt) {
            int r = arow + mt * 16;
            int qp = quad ^ ((r >> 1) & 3);
            af[mt] = *(half8*)&sA[r * 32 + qp * 8];
        }
        #pragma unroll
        for (int nt = 0; nt < 4; ++nt) {
            int r = brow + nt * 16;
            int qp = quad ^ ((r >> 1) & 3);
            bf[nt] = *(half8*)&sB[r * 32 + qp * 8];
        }
        #pragma unroll
        for (int mt = 0; mt < 4; ++mt)
            #pragma unroll
            for (int nt = 0; nt < 4; ++nt)
                acc[mt][nt] = __builtin_amdgcn_mfma_f32_16x16x32_f16(af[mt], bf[nt], acc[mt][nt], 0, 0, 0);
        __syncthreads();
    }

    _Float16* qfr = PL;
    _Float16* qfi = PL + 1048576;
    _Float16* gqp = PL + 2097152;
    _Float16* kkr = PL + 3145728;
    _Float16* kki = PL + 4194304;
    _Float16* gkp = PL + 5242880;
    _Float16* vrp = PL + 6291456;
    _Float16* vip = PL + 7340032;

    const int crow0 = m0 + wm * 64 + quad * 4;
    #pragma unroll
    for (int j = 0; j < 2; ++j) {
        int col = nb + wn * 32 + j * 16 + l15;
        float bre = ball[R0 + wn * 64 + j * 32 + l15];
        float bim = ball[R0 + wn * 64 + j * 32 + 16 + l15];
        #pragma unroll
        for (int mt = 0; mt < 4; ++mt) {
            #pragma unroll
            for (int reg = 0; reg < 4; ++reg) {
                int row = crow0 + mt * 16 + reg;
                size_t ofs = (size_t)row * 512 + col;
                float xr = acc[mt][2 * j][reg] + bre;
                float xi = acc[mt][2 * j + 1][reg] + bim;
                if (g == 0) {
                    float gv = sqrtf(xr * xr + xi * xi);
                    float f = gv / (gv + EPS_F);
                    qfr[ofs] = (_Float16)(xr * f);
                    qfi[ofs] = (_Float16)(xi * f);
                    gqp[ofs] = (_Float16)gv;
                } else if (g == 1) {
                    float gv = sqrtf(xr * xr + xi * xi);
                    float f = gv / (gv + EPS_F);
                    kkr[ofs] = (_Float16)(xr * f);
                    kki[ofs] = (_Float16)(-xi * f);   // conj
                    gkp[ofs] = (_Float16)gv;
                } else {
                    vrp[ofs] = (_Float16)xr;
                    vip[ofs] = (_Float16)xi;
                }
            }
        }
    }
}

// ---------------------------------------------------------------------------
// GEMM2 (round-5-proven reg-staging): out = Y2h @ W2T^T + b2a
// ---------------------------------------------------------------------------
__global__ __launch_bounds__(256) void gemm_f16_kernel(
    const _Float16* __restrict__ A,
    const _Float16* __restrict__ BT,
    const float* __restrict__ bias,
    float* __restrict__ C,
    int K, int ldc, int wmode)
{
    __shared__ _Float16 sA[128 * 32];
    __shared__ _Float16 sB[128 * 32];
    const int tid = threadIdx.x;
    const int m0 = blockIdx.y * 128, n0 = blockIdx.x * 128;
    const int lane = tid & 63;
    const int w = tid >> 6, wm = w >> 1, wn = w & 1;

    f32x4 acc[4][4];
    #pragma unroll
    for (int i = 0; i < 4; ++i)
        #pragma unroll
        for (int j = 0; j < 4; ++j) { f32x4 z = {0.f, 0.f, 0.f, 0.f}; acc[i][j] = z; }

    const int r0 = tid >> 2, r1 = (tid >> 2) + 64;
    const int sq = tid & 3;
    const _Float16* gA0 = A + (size_t)(m0 + r0) * K + (sq ^ ((r0 >> 1) & 3)) * 8;
    const _Float16* gA1 = A + (size_t)(m0 + r1) * K + (sq ^ ((r1 >> 1) & 3)) * 8;
    const _Float16* gB0 = BT + (size_t)(n0 + r0) * K + (sq ^ ((r0 >> 1) & 3)) * 8;
    const _Float16* gB1 = BT + (size_t)(n0 + r1) * K + (sq ^ ((r1 >> 1) & 3)) * 8;
    _Float16* wA0 = &sA[r0 * 32 + sq * 8];
    _Float16* wA1 = &sA[r1 * 32 + sq * 8];
    _Float16* wB0 = &sB[r0 * 32 + sq * 8];
    _Float16* wB1 = &sB[r1 * 32 + sq * 8];

    float4 pa0 = *(const float4*)gA0, pa1 = *(const float4*)gA1;
    float4 pb0 = *(const float4*)gB0, pb1 = *(const float4*)gB1;

    const int arow = wm * 64 + (lane & 15);
    const int brow = wn * 64 + (lane & 15);
    const int nsteps = K >> 5;

    for (int ks = 0; ks < nsteps; ++ks) {
        *(float4*)wA0 = pa0; *(float4*)wA1 = pa1;
        *(float4*)wB0 = pb0; *(float4*)wB1 = pb1;
        __syncthreads();
        if (ks + 1 < nsteps) {
            int ko = (ks + 1) << 5;
            pa0 = *(const float4*)(gA0 + ko); pa1 = *(const float4*)(gA1 + ko);
            pb0 = *(const float4*)(gB0 + ko); pb1 = *(const float4*)(gB1 + ko);
        }
        half8 af[4], bf[4];
        #pragma unroll
        for (int mt = 0; mt < 4; ++mt) {
            int r = arow + mt * 16;
            int qp = (lane >> 4) ^ ((r >> 1) & 3);
            af[mt] = *(half8*)&sA[r * 32 + qp * 8];
        }
        #pragma unroll
        for (int nt = 0; nt < 4; ++nt) {
            int r = brow + nt * 16;
            int qp = (lane >> 4) ^ ((r >> 1) & 3);
            bf[nt] = *(half8*)&sB[r * 32 + qp * 8];
        }
        #pragma unroll
        for (int mt = 0; mt < 4; ++mt)
            #pragma unroll
            for (int nt = 0; nt < 4; ++nt)
                acc[mt][nt] = __builtin_amdgcn_mfma_f32_16x16x32_f16(af[mt], bf[nt], acc[mt][nt], 0, 0, 0);
        __syncthreads();
    }

    const int crow0 = m0 + wm * 64 + (lane >> 4) * 4;
    const int ccol0 = n0 + wn * 64 + (lane & 15);
    #pragma unroll
    for (int mt = 0; mt < 4; ++mt) {
        #pragma unroll
        for (int nt = 0; nt < 4; ++nt) {
            int col = ccol0 + nt * 16;
            float b = bias[col];
            #pragma unroll
            for (int rg = 0; rg < 4; ++rg) {
                int row = crow0 + mt * 16 + rg;
                float val = acc[mt][nt][rg] + b;
                if (wmode == 0) {
                    C[(size_t)row * ldc + col] = val;
                } else {
                    int off = (col < 512) ? (row * 1024 + 2 * col) : (row * 1024 + 2 * (col - 512) + 1);
                    C[off] = val;
                }
            }
        }
    }
}

// ---------------------------------------------------------------------------
// chunkstate: MFMA, reads fp16 planes, writes Sc packed half2 (uint).
// Negations on register fragments.
// ---------------------------------------------------------------------------
__global__ __launch_bounds__(256) void chunkstate_kernel(
    const _Float16* __restrict__ PL,
    const float* __restrict__ lgs, const float* __restrict__ lgz,
    const float* __restrict__ phs,
    unsigned int* __restrict__ ScU, float* __restrict__ Zc)
{
    __shared__ _Float16 wvTr[64 * 40], wvTi[64 * 40];      // [vd][u]
    __shared__ _Float16 kkTr[64 * 40], kkTi[64 * 40];      // [k][u]
    __shared__ float    Lgkz[32 * 65];                     // [u][k]

    const int tid = threadIdx.x;
    const int c = blockIdx.x & 63, h = blockIdx.x >> 6;

    float xs = lgs[h];
    float sps = fmaxf(xs, 0.f) + log1pf(expf(-fabsf(xs)));
    float ph = phs[h];
    float xz = lgz[h];
    float spz = fmaxf(xz, 0.f) + log1pf(expf(-fabsf(xz)));

    const _Float16* kkrP = PL + 3145728;
    const _Float16* kkiP = PL + 4194304;
    const _Float16* gkpP = PL + 5242880;
    const _Float16* vrP  = PL + 6291456;
    const _Float16* viP  = PL + 7340032;

    {
        const int u = tid >> 3, ks = (tid & 7) << 3;
        const size_t rofs = (size_t)(c * CL + u) * 512 + h * HDD + ks;
        half8 kr8 = *(const half8*)&kkrP[rofs];
        half8 ki8 = *(const half8*)&kkiP[rofs];
        half8 gk8 = *(const half8*)&gkpP[rofs];
        half8 vr8 = *(const half8*)&vrP[rofs];
        half8 vi8 = *(const half8*)&viP[rofs];
        float e = (float)(CL - 1 - u);
        float r = expf(-sps * e);
        float wAr = r * cosf(ph * e), wAi = r * sinf(ph * e);
        float wz = expf(-spz * e);
        #pragma unroll
        for (int j = 0; j < 8; ++j) {
            int kcol = ks + j;
            kkTr[kcol * 40 + u] = kr8[j];
            kkTi[kcol * 40 + u] = ki8[j];
            float vre = (float)vr8[j], vim = (float)vi8[j];
            wvTr[kcol * 40 + u] = (_Float16)(wAr * vre - wAi * vim);
            wvTi[kcol * 40 + u] = (_Float16)(wAr * vim + wAi * vre);
            Lgkz[u * 65 + kcol] = wz * (float)gk8[j];
        }
    }
    __syncthreads();

    const int w = tid >> 6, lane = tid & 63;
    const int quad = lane >> 4, l15 = lane & 15;
    const int arow = (w * 16 + l15) * 40 + quad * 8;
    half8 fvr = *(const half8*)&wvTr[arow];
    half8 fvi = *(const half8*)&wvTi[arow];
    unsigned int* out = ScU + ((size_t)(c * NH + h) << 12);
    #pragma unroll
    for (int kq = 0; kq < 4; ++kq) {
        int brow = (kq * 16 + l15) * 40 + quad * 8;
        half8 fkr  = *(const half8*)&kkTr[brow];
        half8 fki  = *(const half8*)&kkTi[brow];
        half8 fkiN = neg8r(fki);
        f32x4 Cr = {0.f, 0.f, 0.f, 0.f}, Ci = {0.f, 0.f, 0.f, 0.f};
        Cr = __builtin_amdgcn_mfma_f32_16x16x32_f16(fvr, fkr,  Cr, 0, 0, 0);
        Cr = __builtin_amdgcn_mfma_f32_16x16x32_f16(fvi, fkiN, Cr, 0, 0, 0);
        Ci = __builtin_amdgcn_mfma_f32_16x16x32_f16(fvr, fki,  Ci, 0, 0, 0);
        Ci = __builtin_amdgcn_mfma_f32_16x16x32_f16(fvi, fkr,  Ci, 0, 0, 0);
        #pragma unroll
        for (int reg = 0; reg < 4; ++reg) {
            int vd = w * 16 + quad * 4 + reg;
            out[vd * 64 + kq * 16 + l15] = pack2h(Cr[reg], Ci[reg]);
        }
    }
    if (tid < 64) {
        float z = 0.f;
        #pragma unroll
        for (int uu = 0; uu < 32; ++uu) z += Lgkz[uu * 65 + tid];
        Zc[(c * NH + h) * 64 + tid] = z;
    }
}

// ---------------------------------------------------------------------------
// chunkscan: exclusive prefix over chunks, packed half2 state, batch-8 loads.
// ---------------------------------------------------------------------------
__global__ __launch_bounds__(256) void chunkscan_kernel(
    const float* __restrict__ lgs, const float* __restrict__ lgz,
    const float* __restrict__ phs,
    unsigned int* __restrict__ ScU, float* __restrict__ Zc)
{
    const int bid = blockIdx.x, tid = threadIdx.x;
    if (bid < 128) {
        const int idx = bid * 256 + tid;
        const int h = idx >> 12, e = idx & 4095;
        float xs = lgs[h];
        float sps = fmaxf(xs, 0.f) + log1pf(expf(-fabsf(xs)));
        float ph = phs[h];
        float r = expf(-sps * (float)CL);
        float aLr = r * cosf(ph * (float)CL), aLi = r * sinf(ph * (float)CL);
        unsigned int* p = ScU + (size_t)h * 4096 + e;
        float pr = 0.f, pi = 0.f;
        #pragma unroll
        for (int cb = 0; cb < 8; ++cb) {
            unsigned int v[8];
            #pragma unroll
            for (int j = 0; j < 8; ++j) v[j] = p[(size_t)((cb << 3) + j) * 32768];
            #pragma unroll
            for (int j = 0; j < 8; ++j) {
                float2 tmp = unpack2h(v[j]);
                p[(size_t)((cb << 3) + j) * 32768] = pack2h(pr, pi);
                float nr = aLr * pr - aLi * pi + tmp.x;
                float ni = aLr * pi + aLi * pr + tmp.y;
                pr = nr; pi = ni;
            }
        }
    } else {
        const int idx = (bid - 128) * 256 + tid;
        const int h = idx >> 6, k = idx & 63;
        float xz = lgz[h];
        float spz = fmaxf(xz, 0.f) + log1pf(expf(-fabsf(xz)));
        float azL = expf(-spz * (float)CL);
        float* p = Zc + h * 64 + k;
        float prev = 0.f;
        #pragma unroll
        for (int cb = 0; cb < 8; ++cb) {
            float v[8];
            #pragma unroll
            for (int j = 0; j < 8; ++j) v[j] = p[(size_t)((cb << 3) + j) * 512];
            #pragma unroll
            for (int j = 0; j < 8; ++j) {
                float tmp = v[j];
                p[(size_t)((cb << 3) + j) * 512] = prev;
                prev = azL * prev + tmp;
            }
        }
    }
}

// ---------------------------------------------------------------------------
// chunkout v4: Sp fragments loaded directly from global into registers;
// fp16 negations in registers; LDS ~44KB.
// ---------------------------------------------------------------------------
__global__ __launch_bounds__(256) void chunkout_kernel(
    const _Float16* __restrict__ PL,
    const unsigned int* __restrict__ SpU, const float* __restrict__ Zp,
    const float* __restrict__ lgs, const float* __restrict__ lgz,
    const float* __restrict__ phs,
    _Float16* __restrict__ Y2h)
{
    __shared__ _Float16 Lqr[32 * 72], Lqi[32 * 72];   // [t][k]
    __shared__ _Float16 Lkr[32 * 72], Lki[32 * 72];   // [u][k]
    __shared__ _Float16 Lgq[32 * 72], Lgk[32 * 72];
    __shared__ _Float16 Vtr[64 * 40], Vti[64 * 40];   // [vd][u]
    __shared__ _Float16 Wr_[32 * 40], Wi_[32 * 40];   // [t][u]
    __shared__ float  sDenP[2][32], sZdot[32], sDinv[32], sZp[64];
    __shared__ float2 s_apow[CL + 1];
    __shared__ float  s_azpow[CL + 1];

    const int tid = threadIdx.x;
    const int c = blockIdx.x & 63, h = blockIdx.x >> 6;
    const int w = tid >> 6, lane = tid & 63;
    const int quad = lane >> 4, l15 = lane & 15;

    // ---- Sp fragment prefetch (global -> regs), overlaps staging ----
    uint4 spv[4];
    {
        const unsigned int* bp = SpU + ((size_t)(c * NH + h) << 12) + (w * 16 + l15) * 64;
        #pragma unroll
        for (int s = 0; s < 2; ++s) {
            spv[s * 2]     = *(const uint4*)(bp + s * 32 + quad * 8);
            spv[s * 2 + 1] = *(const uint4*)(bp + s * 32 + quad * 8 + 4);
        }
    }

    if (tid <= CL) {
        float xs = lgs[h];
        float sps = fmaxf(xs, 0.f) + log1pf(expf(-fabsf(xs)));
        float ph = phs[h];
        float r = expf(-sps * (float)tid);
        s_apow[tid] = make_float2(r * cosf(ph * (float)tid), r * sinf(ph * (float)tid));
        float xz = lgz[h];
        float spz = fmaxf(xz, 0.f) + log1pf(expf(-fabsf(xz)));
        s_azpow[tid] = expf(-spz * (float)tid);
    }
    if (tid < 64) sZp[tid] = Zp[(c * NH + h) * 64 + tid];

    const _Float16* qfrP = PL;
    const _Float16* qfiP = PL + 1048576;
    const _Float16* gqpP = PL + 2097152;
    const _Float16* kkrP = PL + 3145728;
    const _Float16* kkiP = PL + 4194304;
    const _Float16* gkpP = PL + 5242880;
    const _Float16* vrP  = PL + 6291456;
    const _Float16* viP  = PL + 7340032;

    {
        const int u = tid >> 3, ks = (tid & 7) << 3;
        const size_t rofs = (size_t)(c * CL + u) * 512 + h * HDD + ks;
        half8 qr  = *(const half8*)&qfrP[rofs];
        half8 qi  = *(const half8*)&qfiP[rofs];
        half8 g8q = *(const half8*)&gqpP[rofs];
        half8 kr  = *(const half8*)&kkrP[rofs];
        half8 ki  = *(const half8*)&kkiP[rofs];
        half8 g8k = *(const half8*)&gkpP[rofs];
        half8 vr8 = *(const half8*)&vrP[rofs];
        half8 vi8 = *(const half8*)&viP[rofs];
        int ofs = u * 72 + ks;
        *(half8*)&Lqr[ofs] = qr;  *(half8*)&Lqi[ofs] = qi;
        *(half8*)&Lkr[ofs] = kr;  *(half8*)&Lki[ofs] = ki;
        *(half8*)&Lgq[ofs] = g8q; *(half8*)&Lgk[ofs] = g8k;
        #pragma unroll
        for (int j = 0; j < 8; ++j) {
            Vtr[(ks + j) * 40 + u] = vr8[j];
            Vti[(ks + j) * 40 + u] = vi8[j];
        }
    }
    __syncthreads();

    // ---- zdot[t] = Zp . gq[t] ----
    {
        const int t = tid >> 3, k8 = (tid & 7) << 3;
        float z = 0.f;
        #pragma unroll
        for (int j = 0; j < 8; ++j) z += sZp[k8 + j] * (float)Lgq[t * 72 + k8 + j];
        z += __shfl_xor(z, 1); z += __shfl_xor(z, 2); z += __shfl_xor(z, 4);
        if ((tid & 7) == 0) sZdot[t] = z;
    }

    // ---- unpack Sp fragments ----
    half8 fSr[2], fSi[2], fSiN[2];
    #pragma unroll
    for (int s = 0; s < 2; ++s) {
        unsigned int uu[8];
        *(uint4*)&uu[0] = spv[s * 2];
        *(uint4*)&uu[4] = spv[s * 2 + 1];
        #pragma unroll
        for (int j = 0; j < 8; ++j) {
            union { unsigned int u; _Float16 hh[2]; } z; z.u = uu[j];
            fSr[s][j] = z.hh[0]; fSi[s][j] = z.hh[1];
        }
        fSiN[s] = neg8r(fSi[s]);
    }

    const int th = w >> 1, uh = w & 1;
    const f32x4 zero = {0.f, 0.f, 0.f, 0.f};

    // ---- phase 1a: scores + den ----
    f32x4 Ar = zero, Ai = zero, Dn = zero;
    {
        const int qrow = (th * 16 + l15) * 72;
        const int krow = (uh * 16 + l15) * 72;
        #pragma unroll
        for (int s = 0; s < 2; ++s) {
            int ko = s * 32 + quad * 8;
            half8 fqr  = *(const half8*)&Lqr[qrow + ko];
            half8 fqi  = *(const half8*)&Lqi[qrow + ko];
            half8 fkr  = *(const half8*)&Lkr[krow + ko];
            half8 fki  = *(const half8*)&Lki[krow + ko];
            half8 fkiN = neg8r(fki);
            Ar = __builtin_amdgcn_mfma_f32_16x16x32_f16(fqr, fkr,  Ar, 0, 0, 0);
            Ar = __builtin_amdgcn_mfma_f32_16x16x32_f16(fqi, fkiN, Ar, 0, 0, 0);
            Ai = __builtin_amdgcn_mfma_f32_16x16x32_f16(fqr, fki,  Ai, 0, 0, 0);
            Ai = __builtin_amdgcn_mfma_f32_16x16x32_f16(fqi, fkr,  Ai, 0, 0, 0);
            half8 fgq = *(const half8*)&Lgq[qrow + ko];
            half8 fgk = *(const half8*)&Lgk[krow + ko];
            Dn = __builtin_amdgcn_mfma_f32_16x16x32_f16(fgq, fgk, Dn, 0, 0, 0);
        }
    }
    // ---- phase 1b: inter = Sp @ qf (Sp frags in registers) ----
    f32x4 IRr[2] = {zero, zero}, IRi[2] = {zero, zero};
    #pragma unroll
    for (int s = 0; s < 2; ++s) {
        int ko = s * 32 + quad * 8;
        #pragma unroll
        for (int t2 = 0; t2 < 2; ++t2) {
            int qrow = (t2 * 16 + l15) * 72 + ko;
            half8 fqr = *(const half8*)&Lqr[qrow];
            half8 fqi = *(const half8*)&Lqi[qrow];
            IRr[t2] = __builtin_amdgcn_mfma_f32_16x16x32_f16(fSr[s],  fqr, IRr[t2], 0, 0, 0);
            IRr[t2] = __builtin_amdgcn_mfma_f32_16x16x32_f16(fSiN[s], fqi, IRr[t2], 0, 0, 0);
            IRi[t2] = __builtin_amdgcn_mfma_f32_16x16x32_f16(fSr[s],  fqi, IRi[t2], 0, 0, 0);
            IRi[t2] = __builtin_amdgcn_mfma_f32_16x16x32_f16(fSi[s],  fqr, IRi[t2], 0, 0, 0);
        }
    }
    // ---- mask + decay -> Wr_/Wi_; den partials ----
    #pragma unroll
    for (int reg = 0; reg < 4; ++reg) {
        int t = th * 16 + quad * 4 + reg;
        int u = uh * 16 + l15;
        float wr = 0.f, wi = 0.f, dd = 0.f;
        if (u <= t) {
            float2 p = s_apow[t - u];
            wr = p.x * Ar[reg] - p.y * Ai[reg];
            wi = p.x * Ai[reg] + p.y * Ar[reg];
            dd = s_azpow[t - u] * Dn[reg];
        }
        Wr_[t * 40 + u] = (_Float16)wr;
        Wi_[t * 40 + u] = (_Float16)wi;
        dd += __shfl_xor(dd, 1); dd += __shfl_xor(dd, 2);
        dd += __shfl_xor(dd, 4); dd += __shfl_xor(dd, 8);
        if (l15 == 0) sDenP[uh][t] = dd;
    }
    __syncthreads();

    if (tid < 32) {
        float den = sDenP[0][tid] + sDenP[1][tid] + s_azpow[tid + 1] * sZdot[tid];
        sDinv[tid] = 1.f / (den + EPS_F);
    }

    // ---- phase 2: intra = vT @ sW^T ----
    f32x4 NRr[2] = {zero, zero}, NRi[2] = {zero, zero};
    {
        const int vrow = (w * 16 + l15) * 40 + quad * 8;
        half8 fvr = *(const half8*)&Vtr[vrow];
        half8 fvi = *(const half8*)&Vti[vrow];
        half8 fviN = neg8r(fvi);
        #pragma unroll
        for (int t2 = 0; t2 < 2; ++t2) {
            int trow = (t2 * 16 + l15) * 40 + quad * 8;
            half8 fWr = *(const half8*)&Wr_[trow];
            half8 fWi = *(const half8*)&Wi_[trow];
            NRr[t2] = __builtin_amdgcn_mfma_f32_16x16x32_f16(fvr,  fWr, NRr[t2], 0, 0, 0);
            NRr[t2] = __builtin_amdgcn_mfma_f32_16x16x32_f16(fviN, fWi, NRr[t2], 0, 0, 0);
            NRi[t2] = __builtin_amdgcn_mfma_f32_16x16x32_f16(fvr,  fWi, NRi[t2], 0, 0, 0);
            NRi[t2] = __builtin_amdgcn_mfma_f32_16x16x32_f16(fvi,  fWr, NRi[t2], 0, 0, 0);
        }
    }
    __syncthreads();

    // ---- epilogue ----
    #pragma unroll
    for (int t2 = 0; t2 < 2; ++t2) {
        int t = t2 * 16 + l15;
        float2 fac = s_apow[t + 1];
        float dinv = sDinv[t];
        half4 hre, him;
        #pragma unroll
        for (int reg = 0; reg < 4; ++reg) {
            float rx = NRr[t2][reg] + fac.x * IRr[t2][reg] - fac.y * IRi[t2][reg];
            float ry = NRi[t2][reg] + fac.x * IRi[t2][reg] + fac.y * IRr[t2][reg];
            hre[reg] = (_Float16)(rx * dinv);
            him[reg] = (_Float16)(ry * dinv);
        }
        int vd0 = w * 16 + quad * 4;
        _Float16* orow = Y2h + (size_t)(c * CL + t) * 1024 + h * HDD;
        *(half4*)&orow[vd0]       = hre;
        *(half4*)&orow[512 + vd0] = him;
    }
}

// ---------------------------------------------------------------------------
extern "C" void kernel_launch(void* const* d_in, const int* in_sizes, int n_in,
                              void* d_out, int out_size, void* d_ws, size_t ws_size,
                              hipStream_t stream)
{
    const float* x    = (const float*)d_in[0];
    const float* q_wr = (const float*)d_in[1];
    const float* q_wi = (const float*)d_in[2];
    const float* q_br = (const float*)d_in[3];
    const float* q_bi = (const float*)d_in[4];
    const float* k_wr = (const float*)d_in[5];
    const float* k_wi = (const float*)d_in[6];
    const float* k_br = (const float*)d_in[7];
    const float* k_bi = (const float*)d_in[8];
    const float* v_wr = (const float*)d_in[9];
    const float* v_wi = (const float*)d_in[10];
    const float* v_br = (const float*)d_in[11];
    const float* v_bi = (const float*)d_in[12];
    const float* o_wr = (const float*)d_in[13];
    const float* o_wi = (const float*)d_in[14];
    const float* o_br = (const float*)d_in[15];
    const float* o_bi = (const float*)d_in[16];
    const float* log_decay_s = (const float*)d_in[17];
    const float* log_decay_z = (const float*)d_in[18];
    const float* phase       = (const float*)d_in[19];

    float* ws = (float*)d_ws;
    float* Zcf  = ws;                          // 32768 f
    float* ball = ws + 32768;                  // 3072 f
    float* b2a  = ws + 35840;                  // 1024 f
    _Float16* WTa = (_Float16*)(ws + 36864);   // 1572864 h
    _Float16* W2T = WTa + 1572864;             // 1048576 h
    _Float16* Y2h = W2T + 1048576;             // 2097152 h
    _Float16* PL  = Y2h + 2097152;             // 8 x 1048576 h
    unsigned int* ScU = (unsigned int*)(PL + 8388608);  // 2097152 u32

    int out_mode = (out_size == 2048 * 1024) ? 1 : 0;

    prep_kernel<<<656, 256, 0, stream>>>(q_wr, q_wi, k_wr, k_wi, v_wr, v_wi,
                                         o_wr, o_wi, q_br, q_bi, k_br, k_bi,
                                         v_br, v_bi, o_br, o_bi,
                                         WTa, W2T, ball, b2a);

    gemm_qkv_kernel<<<dim3(24, 16), 256, 0, stream>>>(x, WTa, ball, PL);

    chunkstate_kernel<<<512, 256, 0, stream>>>(PL, log_decay_s, log_decay_z, phase,
                                               ScU, Zcf);

    chunkscan_kernel<<<130, 256, 0, stream>>>(log_decay_s, log_decay_z, phase, ScU, Zcf);

    chunkout_kernel<<<512, 256, 0, stream>>>(PL, ScU, Zcf, log_decay_s, log_decay_z,
                                             phase, Y2h);

    if (out_mode == 1) {
        gemm_f16_kernel<<<dim3(8, 16), 256, 0, stream>>>(Y2h, W2T, b2a, (float*)d_out,
                                                         1024, 1024, 1);
    } else {
        gemm_f16_kernel<<<dim3(4, 16), 256, 0, stream>>>(Y2h, W2T, b2a, (float*)d_out,
                                                         1024, 512, 0);
    }
}